// Round 4
// baseline (730.635 us; speedup 1.0000x reference)
//
#include <hip/hip_runtime.h>
#include <hip/hip_bf16.h>

// Problem constants
#define B_  2
#define V_  4
#define Hin 480
#define Win 640
#define H2  240   // after conv1 (s2)
#define W2  320
#define H4  120   // after conv2 (s2)
#define W4  160
#define C1  32
#define C_  64
#define D_  5
#define NIMG 10  // B + B*V

// ---------------- workspace layout (float offsets) ----------------
#define OFF_F1   0
#define OFF_F2   24576000
#define OFF_F3   0
#define OFF_GEOM 36864000
#define OFF_W1T  36864128
#define OFF_W2T  36868864
#define OFF_W3T  36887296

// ---------------- weight transpose: [co][ci][kh][kw] -> [ci][kh][kw][co] ----
__global__ void tw_kernel(const float* __restrict__ w, float* __restrict__ wt,
                          int CO, int CI, int KH, int KW) {
    int idx = blockIdx.x * 256 + threadIdx.x;
    int total = CO * CI * KH * KW;
    if (idx >= total) return;
    int co = idx % CO;
    int r = idx / CO;
    int kx = r % KW; r /= KW;
    int ky = r % KH; r /= KH;
    int ci = r;
    wt[idx] = w[((co * CI + ci) * KH + ky) * KW + kx];
}

// ---------------- geometry: A = K R Kinv, c = K t ----------------
__global__ void geom_kernel(const float* __restrict__ poses,
                            const float* __restrict__ Kmat,
                            float* __restrict__ geom) {
    int i = threadIdx.x;         // (b*V + v)
    if (i >= B_ * V_) return;
    int b = i / V_;
    const float* Kb = Kmat + b * 9;
    float k00=Kb[0],k01=Kb[1],k02=Kb[2];
    float k10=Kb[3],k11=Kb[4],k12=Kb[5];
    float k20=Kb[6],k21=Kb[7],k22=Kb[8];
    float det = k00*(k11*k22-k12*k21) - k01*(k10*k22-k12*k20) + k02*(k10*k21-k11*k20);
    float id = 1.0f / det;
    float ki[9];
    ki[0]=(k11*k22-k12*k21)*id; ki[1]=(k02*k21-k01*k22)*id; ki[2]=(k01*k12-k02*k11)*id;
    ki[3]=(k12*k20-k10*k22)*id; ki[4]=(k00*k22-k02*k20)*id; ki[5]=(k02*k10-k00*k12)*id;
    ki[6]=(k10*k21-k11*k20)*id; ki[7]=(k01*k20-k00*k21)*id; ki[8]=(k00*k11-k01*k10)*id;
    const float* P = poses + i * 16;
    float R[9] = {P[0],P[1],P[2], P[4],P[5],P[6], P[8],P[9],P[10]};
    float t[3] = {P[3],P[7],P[11]};
    float KR[9];
    for (int r = 0; r < 3; r++)
        for (int c = 0; c < 3; c++)
            KR[r*3+c] = Kb[r*3+0]*R[0*3+c] + Kb[r*3+1]*R[1*3+c] + Kb[r*3+2]*R[2*3+c];
    float* g = geom + i * 12;
    for (int r = 0; r < 3; r++)
        for (int c = 0; c < 3; c++)
            g[r*3+c] = KR[r*3+0]*ki[0*3+c] + KR[r*3+1]*ki[1*3+c] + KR[r*3+2]*ki[2*3+c];
    for (int r = 0; r < 3; r++)
        g[9+r] = Kb[r*3+0]*t[0] + Kb[r*3+1]*t[1] + Kb[r*3+2]*t[2];
}

// ---------------- conv1: 3->32, 7x7, s2, p3, ReLU. out NCHW ----------------
// 2 out-pixels x 16 out-channels per thread; blockIdx.z = n*2 + chunk
__global__ void conv1_kernel(const float* __restrict__ ref, const float* __restrict__ ngh,
                             const float* __restrict__ w1t, const float* __restrict__ b1,
                             float* __restrict__ out) {
    const int gx = blockIdx.x * 16 + threadIdx.x;   // pixel-pair index
    const int oy = blockIdx.y * 16 + threadIdx.y;
    const int n  = blockIdx.z >> 1;
    const int c0 = (blockIdx.z & 1) * 16;
    const int px0 = gx * 2;
    const float* in = (n < B_) ? (ref + (size_t)n * 3 * Hin * Win)
                               : (ngh + (size_t)(n - B_) * 3 * Hin * Win);
    float acc0[16], acc1[16];
#pragma unroll
    for (int i = 0; i < 16; i++) { acc0[i] = b1[c0 + i]; acc1[i] = acc0[i]; }
    const int base = px0 * 2 - 3;   // input x of v[0]
    for (int ci = 0; ci < 3; ci++) {
#pragma unroll
        for (int ky = 0; ky < 7; ky++) {
            int iy = oy * 2 - 3 + ky;
            if (iy < 0 || iy >= Hin) continue;
            const float* row = in + ((size_t)ci * Hin + iy) * Win;
            float v[9];
#pragma unroll
            for (int j = 0; j < 9; j++) {
                int ix = base + j;
                v[j] = (ix >= 0 && ix < Win) ? row[ix] : 0.0f;
            }
            const float* wp = w1t + ((ci * 7 + ky) * 7) * C1 + c0;
#pragma unroll
            for (int kx = 0; kx < 7; kx++) {
                float a = v[kx], bb = v[kx + 2];
#pragma unroll
                for (int i = 0; i < 16; i++) {
                    float wv = wp[kx * C1 + i];
                    acc0[i] += a * wv;
                    acc1[i] += bb * wv;
                }
            }
        }
    }
#pragma unroll
    for (int i = 0; i < 16; i++) {
        float* op = out + (((size_t)n * C1 + c0 + i) * H2 + oy) * W2 + px0;
        op[0] = fmaxf(acc0[i], 0.0f);
        op[1] = fmaxf(acc1[i], 0.0f);
    }
}

// ---------------- conv2: 32->64, 3x3, s2, p1, ReLU. out NCHW ----------------
// 2 out-pixels x 16 out-channels per thread; blockIdx.z = n*4 + chunk
__global__ void conv2_kernel(const float* __restrict__ in, const float* __restrict__ w2t,
                             const float* __restrict__ b2, float* __restrict__ out) {
    const int gx = blockIdx.x * 16 + threadIdx.x;   // pixel-pair index (0..79)
    const int oy = blockIdx.y * 16 + threadIdx.y;
    const int n  = blockIdx.z >> 2;
    const int c0 = (blockIdx.z & 3) * 16;
    if (oy >= H4) return;
    const int px0 = gx * 2;
    const float* inp = in + (size_t)n * C1 * H2 * W2;
    float acc0[16], acc1[16];
#pragma unroll
    for (int i = 0; i < 16; i++) { acc0[i] = b2[c0 + i]; acc1[i] = acc0[i]; }
    const int base = px0 * 2 - 1;
#pragma unroll 2
    for (int ci = 0; ci < C1; ci++) {
        const float* icp = inp + (size_t)ci * H2 * W2;
#pragma unroll
        for (int ky = 0; ky < 3; ky++) {
            int iy = oy * 2 - 1 + ky;
            if (iy < 0 || iy >= H2) continue;
            const float* row = icp + (size_t)iy * W2;
            float v[5];
#pragma unroll
            for (int j = 0; j < 5; j++) {
                int ix = base + j;
                v[j] = (ix >= 0 && ix < W2) ? row[ix] : 0.0f;
            }
            const float* wp = w2t + ((ci * 3 + ky) * 3) * C_ + c0;
#pragma unroll
            for (int kx = 0; kx < 3; kx++) {
                float a = v[kx], bb = v[kx + 2];
#pragma unroll
                for (int i = 0; i < 16; i++) {
                    float wv = wp[kx * C_ + i];
                    acc0[i] += a * wv;
                    acc1[i] += bb * wv;
                }
            }
        }
    }
#pragma unroll
    for (int i = 0; i < 16; i++) {
        float* op = out + (((size_t)n * C_ + c0 + i) * H4 + oy) * W4 + px0;
        op[0] = fmaxf(acc0[i], 0.0f);
        op[1] = fmaxf(acc1[i], 0.0f);
    }
}

// ---------------- conv3: 64->64, 3x3, s1, p1, no act. out NHWC --------------
// 2 out-pixels x 16 out-channels per thread; blockIdx.z = n*4 + chunk
__global__ void conv3_kernel(const float* __restrict__ in, const float* __restrict__ w3t,
                             const float* __restrict__ b3, float* __restrict__ out) {
    const int gx = blockIdx.x * 16 + threadIdx.x;   // pixel-pair index (0..79)
    const int oy = blockIdx.y * 16 + threadIdx.y;
    const int n  = blockIdx.z >> 2;
    const int c0 = (blockIdx.z & 3) * 16;
    if (oy >= H4) return;
    const int px0 = gx * 2;
    const float* inp = in + (size_t)n * C_ * H4 * W4;
    float acc0[16], acc1[16];
#pragma unroll
    for (int i = 0; i < 16; i++) { acc0[i] = b3[c0 + i]; acc1[i] = acc0[i]; }
    const int base = px0 - 1;
#pragma unroll 2
    for (int ci = 0; ci < C_; ci++) {
        const float* icp = inp + (size_t)ci * H4 * W4;
#pragma unroll
        for (int ky = 0; ky < 3; ky++) {
            int iy = oy - 1 + ky;
            if (iy < 0 || iy >= H4) continue;
            const float* row = icp + (size_t)iy * W4;
            float v[4];
#pragma unroll
            for (int j = 0; j < 4; j++) {
                int ix = base + j;
                v[j] = (ix >= 0 && ix < W4) ? row[ix] : 0.0f;
            }
            const float* wp = w3t + ((ci * 3 + ky) * 3) * C_ + c0;
#pragma unroll
            for (int kx = 0; kx < 3; kx++) {
                float a = v[kx], bb = v[kx + 1];
#pragma unroll
                for (int i = 0; i < 16; i++) {
                    float wv = wp[kx * C_ + i];
                    acc0[i] += a * wv;
                    acc1[i] += bb * wv;
                }
            }
        }
    }
    float* op = out + (((size_t)n * H4 + oy) * W4 + px0) * C_ + c0;
#pragma unroll
    for (int i = 0; i < 16; i++) op[i] = acc0[i];
#pragma unroll
    for (int i = 0; i < 16; i++) op[C_ + i] = acc1[i];
}

// ---------------- warp + cost volume. one wave per (b,h,w) ----------------
__global__ void warpcost_kernel(const float* __restrict__ feat,  // NHWC, 10 imgs
                                const float* __restrict__ geom,
                                const float* __restrict__ dc,    // (B,D,H4,W4)
                                const int*   __restrict__ valid, // B*V ints
                                float* __restrict__ out) {
    const int wave = threadIdx.x >> 6;
    const int lane = threadIdx.x & 63;
    int pid = blockIdx.x * 4 + wave;  // 0 .. B*H4*W4-1
    int b = pid / (H4 * W4);
    int rem = pid % (H4 * W4);
    int h = rem / W4;
    int w = rem % W4;

    const float refc = feat[(((size_t)b * H4 + h) * W4 + w) * C_ + lane];

    float dep[D_];
#pragma unroll
    for (int d = 0; d < D_; d++)
        dep[d] = dc[(((size_t)b * D_ + d) * H4 + h) * W4 + w];

    float accv[D_] = {0.f, 0.f, 0.f, 0.f, 0.f};
    float den[D_]  = {0.f, 0.f, 0.f, 0.f, 0.f};

    for (int v = 0; v < V_; v++) {
        if (!valid[b * V_ + v]) continue;
        const float* g = geom + (b * V_ + v) * 12;
        float rx = g[0] * w + g[1] * h + g[2];
        float ry = g[3] * w + g[4] * h + g[5];
        float rz = g[6] * w + g[7] * h + g[8];
        float c0 = g[9], c1 = g[10], c2 = g[11];
        const float* fimg = feat + (size_t)(B_ + b * V_ + v) * H4 * W4 * C_;
#pragma unroll
        for (int d = 0; d < D_; d++) {
            float px = dep[d] * rx + c0;
            float py = dep[d] * ry + c1;
            float pz = dep[d] * rz + c2;
            bool zok = pz > 0.001f;
            float zc = fmaxf(pz, 0.001f);
            float u  = px / zc;
            float vv = py / zc;
            bool inb = (u >= 0.f) && (u <= (float)(W4 - 1)) &&
                       (vv >= 0.f) && (vv <= (float)(H4 - 1));
            if (zok && inb) {   // wave-uniform branch
                float u0f = floorf(u), v0f = floorf(vv);
                float du = u - u0f, dv = vv - v0f;
                int u0 = (int)u0f, v0 = (int)v0f;
                int u1 = min(u0 + 1, W4 - 1), v1 = min(v0 + 1, H4 - 1);
                const float* r00 = fimg + ((size_t)v0 * W4 + u0) * C_;
                const float* r01 = fimg + ((size_t)v0 * W4 + u1) * C_;
                const float* r10 = fimg + ((size_t)v1 * W4 + u0) * C_;
                const float* r11 = fimg + ((size_t)v1 * W4 + u1) * C_;
                float f00 = r00[lane], f01 = r01[lane];
                float f10 = r10[lane], f11 = r11[lane];
                float wa = (1.f - du) * (1.f - dv);
                float wb = du * (1.f - dv);
                float wc = (1.f - du) * dv;
                float wd = du * dv;
                accv[d] += f00 * wa + f01 * wb + f10 * wc + f11 * wd;
                den[d]  += 1.f;
            }
        }
    }

#pragma unroll
    for (int d = 0; d < D_; d++) {
        float s = refc * accv[d];
        for (int off = 32; off > 0; off >>= 1) s += __shfl_xor(s, off, 64);
        if (lane == 0) {
            out[(((size_t)b * D_ + d) * H4 + h) * W4 + w] =
                (s * (1.0f / (float)C_)) / fmaxf(den[d], 1.0f);
        }
    }
}

extern "C" void kernel_launch(void* const* d_in, const int* in_sizes, int n_in,
                              void* d_out, int out_size, void* d_ws, size_t ws_size,
                              hipStream_t stream) {
    const float* ref_img  = (const float*)d_in[0];
    const float* ngh_img  = (const float*)d_in[1];
    const float* poses    = (const float*)d_in[2];
    const int*   is_valid = (const int*)  d_in[3];
    const float* K        = (const float*)d_in[4];
    const float* dc       = (const float*)d_in[5];
    const float* w1 = (const float*)d_in[6];
    const float* b1 = (const float*)d_in[7];
    const float* w2 = (const float*)d_in[8];
    const float* b2 = (const float*)d_in[9];
    const float* w3 = (const float*)d_in[10];
    const float* b3 = (const float*)d_in[11];
    float* out = (float*)d_out;

    float* ws = (float*)d_ws;
    float* f1   = ws + OFF_F1;
    float* f2   = ws + OFF_F2;
    float* f3   = ws + OFF_F3;   // overlaps f1 (f1 dead after conv2)
    float* geom = ws + OFF_GEOM;
    float* w1t  = ws + OFF_W1T;
    float* w2t  = ws + OFF_W2T;
    float* w3t  = ws + OFF_W3T;

    geom_kernel<<<1, 64, 0, stream>>>(poses, K, geom);
    tw_kernel<<<(C1*3*7*7 + 255)/256, 256, 0, stream>>>(w1, w1t, C1, 3, 7, 7);
    tw_kernel<<<(C_*C1*3*3 + 255)/256, 256, 0, stream>>>(w2, w2t, C_, C1, 3, 3);
    tw_kernel<<<(C_*C_*3*3 + 255)/256, 256, 0, stream>>>(w3, w3t, C_, C_, 3, 3);

    // conv1: 2px/thread -> 32 px per block-x; W2=320 -> grid.x=10
    conv1_kernel<<<dim3(10, H2/16, NIMG*2), dim3(16,16), 0, stream>>>(ref_img, ngh_img, w1t, b1, f1);
    // conv2/conv3: 32 px per block-x; W4=160 -> grid.x=5
    conv2_kernel<<<dim3(5, (H4+15)/16, NIMG*4), dim3(16,16), 0, stream>>>(f1, w2t, b2, f2);
    conv3_kernel<<<dim3(5, (H4+15)/16, NIMG*4), dim3(16,16), 0, stream>>>(f2, w3t, b3, f3);

    warpcost_kernel<<<(B_*H4*W4)/4, 256, 0, stream>>>(f3, geom, dc, is_valid, out);
}

// Round 5
// 517.640 us; speedup vs baseline: 1.4115x; 1.4115x over previous
//
#include <hip/hip_runtime.h>
#include <hip/hip_bf16.h>

// Problem constants
#define B_  2
#define V_  4
#define Hin 480
#define Win 640
#define H2  240   // after conv1 (s2)
#define W2  320
#define H4  120   // after conv2 (s2)
#define W4  160
#define C1  32
#define C_  64
#define D_  5
#define NIMG 10  // B + B*V

// padded feature dims
#define P1H 242
#define P1W 322
#define P2H 122
#define P2W 162

typedef __attribute__((ext_vector_type(8))) short short8;
typedef __attribute__((ext_vector_type(4))) float f32x4;

// ---------------- workspace layout (float offsets) ----------------
// f1hi (bf16 [10][242][322][32]) @ 0          : 12,467,840 floats
// f1lo                           @ 12,467,840 : 12,467,840
// f2hi (bf16 [10][122][162][64]) @ 24,935,680 :  6,324,480
// f2lo                           @ 31,260,160 :  6,324,480
// f3   (fp32 NHWC 10x19200x64)   @ 0 (overlaps f1hi; f1 dead after conv2)
// geom @ 37,584,640 ; w1t @ 37,584,736 ; w2p @ 37,589,440 ; w3p @ 37,607,872
// total ~ 37,644,736 floats = 150.6 MB
#define OFF_F1HI 0
#define OFF_F1LO 12467840
#define OFF_F2HI 24935680
#define OFF_F2LO 31260160
#define OFF_F3   0
#define OFF_GEOM 37584640
#define OFF_W1T  37584736
#define OFF_W2P  37589440   // ushort[2*18432]: hi then lo
#define OFF_W3P  37607872   // ushort[2*36864]: hi then lo

// ---------------- weight transpose (conv1): [co][ci][kh][kw] -> [ci][kh][kw][co]
__global__ void tw_kernel(const float* __restrict__ w, float* __restrict__ wt,
                          int CO, int CI, int KH, int KW) {
    int idx = blockIdx.x * 256 + threadIdx.x;
    int total = CO * CI * KH * KW;
    if (idx >= total) return;
    int co = idx % CO;
    int r = idx / CO;
    int kx = r % KW; r /= KW;
    int ky = r % KH; r /= KH;
    int ci = r;
    wt[idx] = w[((co * CI + ci) * KH + ky) * KW + kx];
}

// ---------------- pack conv weights into MFMA B-fragment order, bf16 hi/lo ----
// dst[(t*NK + s)*64*8 + lane*8 + j] ; k = s*32 + (lane>>4)*8 + j ; co = t*16 + (lane&15)
// k ordering: k = (ky*3+kx)*CI + ci
__global__ void packw_kernel(const float* __restrict__ w, ushort* __restrict__ dst,
                             int CI, int NK, int lo_off) {
    int idx = blockIdx.x * 256 + threadIdx.x;
    int total = 4 * NK * 64 * 8;
    if (idx >= total) return;
    int j = idx & 7;
    int lane = (idx >> 3) & 63;
    int s = (idx >> 9) % NK;
    int t = idx / (NK * 512);
    int k = s * 32 + (lane >> 4) * 8 + j;
    int co = t * 16 + (lane & 15);
    int kyx = k / CI;
    int ci  = k % CI;
    int ky = kyx / 3, kx = kyx % 3;
    float val = w[((co * CI + ci) * 3 + ky) * 3 + kx];
    __hip_bfloat16 h = __float2bfloat16(val);
    float hf = __bfloat162float(h);
    __hip_bfloat16 l = __float2bfloat16(val - hf);
    dst[idx]          = *reinterpret_cast<ushort*>(&h);
    dst[lo_off + idx] = *reinterpret_cast<ushort*>(&l);
}

// ---------------- zero padded-border cells of f1 and f2 (ws re-poisoned each call)
__global__ void zerob_kernel(ushort* __restrict__ f1hi, ushort* __restrict__ f1lo,
                             ushort* __restrict__ f2hi, ushort* __restrict__ f2lo) {
    const int F1B = 2 * P1W + 2 * (P1H - 2);   // 1124 border px / img
    const int F2B = 2 * P2W + 2 * (P2H - 2);   // 564
    const int f1tot = NIMG * F1B * C1;
    const int f2tot = NIMG * F2B * C_;
    int idx = blockIdx.x * 256 + threadIdx.x;
    if (idx < f1tot) {
        int c = idx & 31; int r = idx >> 5;
        int n = r / F1B; int bp = r % F1B;
        int y, x;
        if (bp < P1W)            { y = 0;        x = bp; }
        else if (bp < 2*P1W)     { y = P1H - 1;  x = bp - P1W; }
        else if (bp < 2*P1W + (P1H-2)) { y = bp - 2*P1W + 1;   x = 0; }
        else                     { y = bp - 2*P1W - (P1H-2) + 1; x = P1W - 1; }
        size_t o = (((size_t)n * P1H + y) * P1W + x) * C1 + c;
        f1hi[o] = 0; f1lo[o] = 0;
        return;
    }
    idx -= f1tot;
    if (idx < f2tot) {
        int c = idx & 63; int r = idx >> 6;
        int n = r / F2B; int bp = r % F2B;
        int y, x;
        if (bp < P2W)            { y = 0;        x = bp; }
        else if (bp < 2*P2W)     { y = P2H - 1;  x = bp - P2W; }
        else if (bp < 2*P2W + (P2H-2)) { y = bp - 2*P2W + 1;   x = 0; }
        else                     { y = bp - 2*P2W - (P2H-2) + 1; x = P2W - 1; }
        size_t o = (((size_t)n * P2H + y) * P2W + x) * C_ + c;
        f2hi[o] = 0; f2lo[o] = 0;
    }
}

// ---------------- geometry: A = K R Kinv, c = K t ----------------
__global__ void geom_kernel(const float* __restrict__ poses,
                            const float* __restrict__ Kmat,
                            float* __restrict__ geom) {
    int i = threadIdx.x;         // (b*V + v)
    if (i >= B_ * V_) return;
    int b = i / V_;
    const float* Kb = Kmat + b * 9;
    float k00=Kb[0],k01=Kb[1],k02=Kb[2];
    float k10=Kb[3],k11=Kb[4],k12=Kb[5];
    float k20=Kb[6],k21=Kb[7],k22=Kb[8];
    float det = k00*(k11*k22-k12*k21) - k01*(k10*k22-k12*k20) + k02*(k10*k21-k11*k20);
    float id = 1.0f / det;
    float ki[9];
    ki[0]=(k11*k22-k12*k21)*id; ki[1]=(k02*k21-k01*k22)*id; ki[2]=(k01*k12-k02*k11)*id;
    ki[3]=(k12*k20-k10*k22)*id; ki[4]=(k00*k22-k02*k20)*id; ki[5]=(k02*k10-k00*k12)*id;
    ki[6]=(k10*k21-k11*k20)*id; ki[7]=(k01*k20-k00*k21)*id; ki[8]=(k00*k11-k01*k10)*id;
    const float* P = poses + i * 16;
    float R[9] = {P[0],P[1],P[2], P[4],P[5],P[6], P[8],P[9],P[10]};
    float t[3] = {P[3],P[7],P[11]};
    float KR[9];
    for (int r = 0; r < 3; r++)
        for (int c = 0; c < 3; c++)
            KR[r*3+c] = Kb[r*3+0]*R[0*3+c] + Kb[r*3+1]*R[1*3+c] + Kb[r*3+2]*R[2*3+c];
    float* g = geom + i * 12;
    for (int r = 0; r < 3; r++)
        for (int c = 0; c < 3; c++)
            g[r*3+c] = KR[r*3+0]*ki[0*3+c] + KR[r*3+1]*ki[1*3+c] + KR[r*3+2]*ki[2*3+c];
    for (int r = 0; r < 3; r++)
        g[9+r] = Kb[r*3+0]*t[0] + Kb[r*3+1]*t[1] + Kb[r*3+2]*t[2];
}

// ---------------- conv1: 3->32, 7x7, s2, p3, ReLU. out padded NHWC bf16 hi/lo
// 1 px x 16 ch per thread; blockIdx.z = n*2 + chunk
__global__ void conv1_kernel(const float* __restrict__ ref, const float* __restrict__ ngh,
                             const float* __restrict__ w1t, const float* __restrict__ b1,
                             ushort* __restrict__ f1hi, ushort* __restrict__ f1lo) {
    const int ox = blockIdx.x * 16 + threadIdx.x;
    const int oy = blockIdx.y * 16 + threadIdx.y;
    const int n  = blockIdx.z >> 1;
    const int c0 = (blockIdx.z & 1) * 16;
    const float* in = (n < B_) ? (ref + (size_t)n * 3 * Hin * Win)
                               : (ngh + (size_t)(n - B_) * 3 * Hin * Win);
    float acc[16];
#pragma unroll
    for (int i = 0; i < 16; i++) acc[i] = b1[c0 + i];
    for (int ci = 0; ci < 3; ci++) {
        for (int ky = 0; ky < 7; ky++) {
            int iy = oy * 2 - 3 + ky;
            if (iy < 0 || iy >= Hin) continue;
            const float* row = in + ((size_t)ci * Hin + iy) * Win;
            for (int kx = 0; kx < 7; kx++) {
                int ix = ox * 2 - 3 + kx;
                float val = (ix >= 0 && ix < Win) ? row[ix] : 0.0f;
                const float* wp = w1t + ((ci * 7 + ky) * 7 + kx) * C1 + c0;
#pragma unroll
                for (int i = 0; i < 16; i++) acc[i] += val * wp[i];
            }
        }
    }
    size_t o = (((size_t)n * P1H + (oy + 1)) * P1W + (ox + 1)) * C1 + c0;
#pragma unroll
    for (int i = 0; i < 16; i++) {
        float v = fmaxf(acc[i], 0.0f);
        __hip_bfloat16 h = __float2bfloat16(v);
        float hf = __bfloat162float(h);
        __hip_bfloat16 l = __float2bfloat16(v - hf);
        f1hi[o + i] = *reinterpret_cast<ushort*>(&h);
        f1lo[o + i] = *reinterpret_cast<ushort*>(&l);
    }
}

// ---------------- conv2 MFMA: 32->64, 3x3, s2, p1, ReLU ----------------
// wave: 16 px x 64 co; block: 4 waves = 64 px; grid (300, NIMG)
__global__ __launch_bounds__(256) void conv2_mfma(
        const ushort* __restrict__ f1hi, const ushort* __restrict__ f1lo,
        const ushort* __restrict__ w2p, const float* __restrict__ b2,
        ushort* __restrict__ f2hi, ushort* __restrict__ f2lo) {
    const int lane = threadIdx.x & 63;
    const int wv   = threadIdx.x >> 6;
    const int n    = blockIdx.y;
    const int px0  = blockIdx.x * 64 + wv * 16;
    const int p    = px0 + (lane & 15);       // A row
    const int y = p / W4, x = p % W4;
    const int kg = lane >> 4;                 // 0..3
    const ushort* ihi = f1hi + (size_t)n * P1H * P1W * C1;
    const ushort* ilo = f1lo + (size_t)n * P1H * P1W * C1;

    f32x4 acc[4] = {};
#pragma unroll
    for (int s = 0; s < 9; s++) {
        const int ky = s / 3, kx = s % 3;
        const int off = ((2 * y + ky) * P1W + (2 * x + kx)) * C1 + kg * 8;
        short8 ahi = *reinterpret_cast<const short8*>(ihi + off);
        short8 alo = *reinterpret_cast<const short8*>(ilo + off);
#pragma unroll
        for (int t = 0; t < 4; t++) {
            const int widx = ((t * 9 + s) * 64 + lane) * 8;
            short8 bhi = *reinterpret_cast<const short8*>(w2p + widx);
            short8 blo = *reinterpret_cast<const short8*>(w2p + 18432 + widx);
            acc[t] = __builtin_amdgcn_mfma_f32_16x16x32_bf16(ahi, bhi, acc[t], 0, 0, 0);
            acc[t] = __builtin_amdgcn_mfma_f32_16x16x32_bf16(ahi, blo, acc[t], 0, 0, 0);
            acc[t] = __builtin_amdgcn_mfma_f32_16x16x32_bf16(alo, bhi, acc[t], 0, 0, 0);
        }
    }
    ushort* ohi = f2hi + (size_t)n * P2H * P2W * C_;
    ushort* olo = f2lo + (size_t)n * P2H * P2W * C_;
#pragma unroll
    for (int t = 0; t < 4; t++) {
        const int co = t * 16 + (lane & 15);
        const float bias = b2[co];
#pragma unroll
        for (int j = 0; j < 4; j++) {
            const int pr = px0 + kg * 4 + j;   // C row = (lane>>4)*4 + j
            const int yy = pr / W4, xx = pr % W4;
            float val = fmaxf(acc[t][j] + bias, 0.0f);
            __hip_bfloat16 h = __float2bfloat16(val);
            float hf = __bfloat162float(h);
            __hip_bfloat16 l = __float2bfloat16(val - hf);
            const size_t o = (((size_t)(yy + 1)) * P2W + (xx + 1)) * C_ + co;
            ohi[o] = *reinterpret_cast<ushort*>(&h);
            olo[o] = *reinterpret_cast<ushort*>(&l);
        }
    }
}

// ---------------- conv3 MFMA: 64->64, 3x3, s1, p1, no act. out NHWC fp32 ----
__global__ __launch_bounds__(256) void conv3_mfma(
        const ushort* __restrict__ f2hi, const ushort* __restrict__ f2lo,
        const ushort* __restrict__ w3p, const float* __restrict__ b3,
        float* __restrict__ f3) {
    const int lane = threadIdx.x & 63;
    const int wv   = threadIdx.x >> 6;
    const int n    = blockIdx.y;
    const int px0  = blockIdx.x * 64 + wv * 16;
    const int p    = px0 + (lane & 15);
    const int y = p / W4, x = p % W4;
    const int kg = lane >> 4;
    const ushort* ihi = f2hi + (size_t)n * P2H * P2W * C_;
    const ushort* ilo = f2lo + (size_t)n * P2H * P2W * C_;

    f32x4 acc[4] = {};
#pragma unroll
    for (int s = 0; s < 18; s++) {
        const int kyx = s >> 1;
        const int ky = kyx / 3, kx = kyx % 3;
        const int ci0 = (s & 1) * 32 + kg * 8;
        const int off = ((y + ky) * P2W + (x + kx)) * C_ + ci0;
        short8 ahi = *reinterpret_cast<const short8*>(ihi + off);
        short8 alo = *reinterpret_cast<const short8*>(ilo + off);
#pragma unroll
        for (int t = 0; t < 4; t++) {
            const int widx = ((t * 18 + s) * 64 + lane) * 8;
            short8 bhi = *reinterpret_cast<const short8*>(w3p + widx);
            short8 blo = *reinterpret_cast<const short8*>(w3p + 36864 + widx);
            acc[t] = __builtin_amdgcn_mfma_f32_16x16x32_bf16(ahi, bhi, acc[t], 0, 0, 0);
            acc[t] = __builtin_amdgcn_mfma_f32_16x16x32_bf16(ahi, blo, acc[t], 0, 0, 0);
            acc[t] = __builtin_amdgcn_mfma_f32_16x16x32_bf16(alo, bhi, acc[t], 0, 0, 0);
        }
    }
    float* op = f3 + (size_t)n * H4 * W4 * C_;
#pragma unroll
    for (int t = 0; t < 4; t++) {
        const int co = t * 16 + (lane & 15);
        const float bias = b3[co];
#pragma unroll
        for (int j = 0; j < 4; j++) {
            const int pr = px0 + kg * 4 + j;
            op[(size_t)pr * C_ + co] = acc[t][j] + bias;
        }
    }
}

// ---------------- warp + cost volume. one wave per (b,h,w) ----------------
__global__ void warpcost_kernel(const float* __restrict__ feat,  // NHWC, 10 imgs
                                const float* __restrict__ geom,
                                const float* __restrict__ dc,    // (B,D,H4,W4)
                                const int*   __restrict__ valid, // B*V ints
                                float* __restrict__ out) {
    const int wave = threadIdx.x >> 6;
    const int lane = threadIdx.x & 63;
    int pid = blockIdx.x * 4 + wave;  // 0 .. B*H4*W4-1
    int b = pid / (H4 * W4);
    int rem = pid % (H4 * W4);
    int h = rem / W4;
    int w = rem % W4;

    const float refc = feat[(((size_t)b * H4 + h) * W4 + w) * C_ + lane];

    float dep[D_];
#pragma unroll
    for (int d = 0; d < D_; d++)
        dep[d] = dc[(((size_t)b * D_ + d) * H4 + h) * W4 + w];

    float accv[D_] = {0.f, 0.f, 0.f, 0.f, 0.f};
    float den[D_]  = {0.f, 0.f, 0.f, 0.f, 0.f};

    for (int v = 0; v < V_; v++) {
        if (!valid[b * V_ + v]) continue;
        const float* g = geom + (b * V_ + v) * 12;
        float rx = g[0] * w + g[1] * h + g[2];
        float ry = g[3] * w + g[4] * h + g[5];
        float rz = g[6] * w + g[7] * h + g[8];
        float c0 = g[9], c1 = g[10], c2 = g[11];
        const float* fimg = feat + (size_t)(B_ + b * V_ + v) * H4 * W4 * C_;
#pragma unroll
        for (int d = 0; d < D_; d++) {
            float px = dep[d] * rx + c0;
            float py = dep[d] * ry + c1;
            float pz = dep[d] * rz + c2;
            bool zok = pz > 0.001f;
            float zc = fmaxf(pz, 0.001f);
            float u  = px / zc;
            float vv = py / zc;
            bool inb = (u >= 0.f) && (u <= (float)(W4 - 1)) &&
                       (vv >= 0.f) && (vv <= (float)(H4 - 1));
            if (zok && inb) {   // wave-uniform branch
                float u0f = floorf(u), v0f = floorf(vv);
                float du = u - u0f, dv = vv - v0f;
                int u0 = (int)u0f, v0 = (int)v0f;
                int u1 = min(u0 + 1, W4 - 1), v1 = min(v0 + 1, H4 - 1);
                const float* r00 = fimg + ((size_t)v0 * W4 + u0) * C_;
                const float* r01 = fimg + ((size_t)v0 * W4 + u1) * C_;
                const float* r10 = fimg + ((size_t)v1 * W4 + u0) * C_;
                const float* r11 = fimg + ((size_t)v1 * W4 + u1) * C_;
                float f00 = r00[lane], f01 = r01[lane];
                float f10 = r10[lane], f11 = r11[lane];
                float wa = (1.f - du) * (1.f - dv);
                float wb = du * (1.f - dv);
                float wc = (1.f - du) * dv;
                float wd = du * dv;
                accv[d] += f00 * wa + f01 * wb + f10 * wc + f11 * wd;
                den[d]  += 1.f;
            }
        }
    }

#pragma unroll
    for (int d = 0; d < D_; d++) {
        float s = refc * accv[d];
        for (int off = 32; off > 0; off >>= 1) s += __shfl_xor(s, off, 64);
        if (lane == 0) {
            out[(((size_t)b * D_ + d) * H4 + h) * W4 + w] =
                (s * (1.0f / (float)C_)) / fmaxf(den[d], 1.0f);
        }
    }
}

extern "C" void kernel_launch(void* const* d_in, const int* in_sizes, int n_in,
                              void* d_out, int out_size, void* d_ws, size_t ws_size,
                              hipStream_t stream) {
    const float* ref_img  = (const float*)d_in[0];
    const float* ngh_img  = (const float*)d_in[1];
    const float* poses    = (const float*)d_in[2];
    const int*   is_valid = (const int*)  d_in[3];
    const float* K        = (const float*)d_in[4];
    const float* dc       = (const float*)d_in[5];
    const float* w1 = (const float*)d_in[6];
    const float* b1 = (const float*)d_in[7];
    const float* w2 = (const float*)d_in[8];
    const float* b2 = (const float*)d_in[9];
    const float* w3 = (const float*)d_in[10];
    const float* b3 = (const float*)d_in[11];
    float* out = (float*)d_out;

    float* ws = (float*)d_ws;
    ushort* f1hi = (ushort*)(ws + OFF_F1HI);
    ushort* f1lo = (ushort*)(ws + OFF_F1LO);
    ushort* f2hi = (ushort*)(ws + OFF_F2HI);
    ushort* f2lo = (ushort*)(ws + OFF_F2LO);
    float*  f3   = ws + OFF_F3;          // overlaps f1 (dead after conv2)
    float*  geom = ws + OFF_GEOM;
    float*  w1t  = ws + OFF_W1T;
    ushort* w2p  = (ushort*)(ws + OFF_W2P);
    ushort* w3p  = (ushort*)(ws + OFF_W3P);

    geom_kernel<<<1, 64, 0, stream>>>(poses, K, geom);
    tw_kernel<<<(C1*3*7*7 + 255)/256, 256, 0, stream>>>(w1, w1t, C1, 3, 7, 7);
    packw_kernel<<<(4*9*64*8 + 255)/256, 256, 0, stream>>>(w2, w2p, C1, 9, 18432);
    packw_kernel<<<(4*18*64*8 + 255)/256, 256, 0, stream>>>(w3, w3p, C_, 18, 36864);
    {
        const int ztot = NIMG*(2*P1W + 2*(P1H-2))*C1 + NIMG*(2*P2W + 2*(P2H-2))*C_;
        zerob_kernel<<<(ztot + 255)/256, 256, 0, stream>>>(f1hi, f1lo, f2hi, f2lo);
    }

    conv1_kernel<<<dim3(W2/16, H2/16, NIMG*2), dim3(16,16), 0, stream>>>(ref_img, ngh_img, w1t, b1, f1hi, f1lo);
    conv2_mfma<<<dim3(H4*W4/64, NIMG), 256, 0, stream>>>(f1hi, f1lo, w2p, b2, f2hi, f2lo);
    conv3_mfma<<<dim3(H4*W4/64, NIMG), 256, 0, stream>>>(f2hi, f2lo, w3p, b3, f3);

    warpcost_kernel<<<(B_*H4*W4)/4, 256, 0, stream>>>(f3, geom, dc, is_valid, out);
}

// Round 6
// 453.552 us; speedup vs baseline: 1.6109x; 1.1413x over previous
//
#include <hip/hip_runtime.h>
#include <hip/hip_bf16.h>

// Problem constants
#define B_  2
#define V_  4
#define Hin 480
#define Win 640
#define H2  240   // after conv1 (s2)
#define W2  320
#define H4  120   // after conv2 (s2)
#define W4  160
#define C1  32
#define C_  64
#define D_  5
#define NIMG 10  // B + B*V

// padded feature dims
#define P1H 242
#define P1W 322
#define P2H 122
#define P2W 162
// padded raw-input dims (for conv1 MFMA)
#define PIH 486
#define PIW 646

typedef __attribute__((ext_vector_type(8))) short short8;
typedef __attribute__((ext_vector_type(4))) float f32x4;

// ---------------- workspace layout (float offsets) ----------------
// f1hi (bf16 [10][242][322][32]) @ 0          : 12,467,840 floats
// f1lo                           @ 12,467,840 : 12,467,840
// f2hi (bf16 [10][122][162][64]) @ 24,935,680 :  6,324,480
// f2lo                           @ 31,260,160 :  6,324,480
// inp_hi (bf16 [10][3][486][646])@ 24,935,680 (ALIAS f2hi region; dead after conv1)
// inp_lo                         @ 29,645,504
// f3   (fp32 NHWC 10x19200x64)   @ 0 (overlaps f1hi; f1 dead after conv2)
// geom @ 37,584,640 ; w1p @ 37,584,736 ; w2p @ 37,590,880 ; w3p @ 37,609,312
// total ~ 37,646,176 floats = 150.6 MB
#define OFF_F1HI 0
#define OFF_F1LO 12467840
#define OFF_F2HI 24935680
#define OFF_F2LO 31260160
#define OFF_INHI 24935680
#define OFF_INLO 29645504
#define OFF_F3   0
#define OFF_GEOM 37584640
#define OFF_W1P  37584736   // ushort[2*6144]: hi then lo
#define OFF_W2P  37590880   // ushort[2*18432]: hi then lo
#define OFF_W3P  37609312   // ushort[2*36864]: hi then lo

// ---------------- pack conv2/conv3 weights into MFMA B-fragment order ----
// dst[(t*NK + s)*64*8 + lane*8 + j] ; k = s*32 + (lane>>4)*8 + j ; co = t*16 + (lane&15)
// k ordering: k = (ky*3+kx)*CI + ci
__global__ void packw_kernel(const float* __restrict__ w, ushort* __restrict__ dst,
                             int CI, int NK, int lo_off) {
    int idx = blockIdx.x * 256 + threadIdx.x;
    int total = 4 * NK * 64 * 8;
    if (idx >= total) return;
    int j = idx & 7;
    int lane = (idx >> 3) & 63;
    int s = (idx >> 9) % NK;
    int t = idx / (NK * 512);
    int k = s * 32 + (lane >> 4) * 8 + j;
    int co = t * 16 + (lane & 15);
    int kyx = k / CI;
    int ci  = k % CI;
    int ky = kyx / 3, kx = kyx % 3;
    float val = w[((co * CI + ci) * 3 + ky) * 3 + kx];
    __hip_bfloat16 h = __float2bfloat16(val);
    float hf = __bfloat162float(h);
    __hip_bfloat16 l = __float2bfloat16(val - hf);
    dst[idx]          = *reinterpret_cast<ushort*>(&h);
    dst[lo_off + idx] = *reinterpret_cast<ushort*>(&l);
}

// ---------------- pack conv1 weights: K-group g=(ci*7+ky) of 8 (kx=j, j=7 pad) ----
// dst[((t*6+s)*64+lane)*8 + j]; g = s*4 + (lane>>4); co = t*16 + (lane&15)
__global__ void packw1_kernel(const float* __restrict__ w, ushort* __restrict__ dst) {
    int idx = blockIdx.x * 256 + threadIdx.x;
    if (idx >= 6144) return;
    int j = idx & 7;
    int lane = (idx >> 3) & 63;
    int s = (idx >> 9) % 6;
    int t = idx / 3072;
    int g = s * 4 + (lane >> 4);
    int co = t * 16 + (lane & 15);
    float val = 0.0f;
    if (g < 21 && j < 7) {
        int ci = g / 7, ky = g % 7;
        val = w[((co * 3 + ci) * 7 + ky) * 7 + j];
    }
    __hip_bfloat16 h = __float2bfloat16(val);
    float hf = __bfloat162float(h);
    __hip_bfloat16 l = __float2bfloat16(val - hf);
    dst[idx]        = *reinterpret_cast<ushort*>(&h);
    dst[6144 + idx] = *reinterpret_cast<ushort*>(&l);
}

// ---------------- pack raw images to padded NCHW bf16 hi/lo ----------------
__global__ void packin_kernel(const float* __restrict__ ref, const float* __restrict__ ngh,
                              ushort* __restrict__ ihi, ushort* __restrict__ ilo) {
    int idx = blockIdx.x * 256 + threadIdx.x;
    const int tot = NIMG * 3 * PIH * PIW;
    if (idx >= tot) return;
    int x = idx % PIW;
    int r = idx / PIW;
    int y = r % PIH;
    int rc = r / PIH;
    int ci = rc % 3;
    int n  = rc / 3;
    float val = 0.0f;
    int lx = x - 3, ly = y - 3;
    if (lx >= 0 && lx < Win && ly >= 0 && ly < Hin) {
        const float* img = (n < B_) ? (ref + ((size_t)n * 3 + ci) * Hin * Win)
                                    : (ngh + ((size_t)(n - B_) * 3 + ci) * Hin * Win);
        val = img[(size_t)ly * Win + lx];
    }
    __hip_bfloat16 h = __float2bfloat16(val);
    float hf = __bfloat162float(h);
    __hip_bfloat16 l = __float2bfloat16(val - hf);
    ihi[idx] = *reinterpret_cast<ushort*>(&h);
    ilo[idx] = *reinterpret_cast<ushort*>(&l);
}

// ---------------- zero padded-border cells of f1 and f2 ----------------
// must run AFTER conv1 (inp aliases f2 region) and BEFORE conv2.
__global__ void zerob_kernel(ushort* __restrict__ f1hi, ushort* __restrict__ f1lo,
                             ushort* __restrict__ f2hi, ushort* __restrict__ f2lo) {
    const int F1B = 2 * P1W + 2 * (P1H - 2);
    const int F2B = 2 * P2W + 2 * (P2H - 2);
    const int f1tot = NIMG * F1B * C1;
    const int f2tot = NIMG * F2B * C_;
    int idx = blockIdx.x * 256 + threadIdx.x;
    if (idx < f1tot) {
        int c = idx & 31; int r = idx >> 5;
        int n = r / F1B; int bp = r % F1B;
        int y, x;
        if (bp < P1W)            { y = 0;        x = bp; }
        else if (bp < 2*P1W)     { y = P1H - 1;  x = bp - P1W; }
        else if (bp < 2*P1W + (P1H-2)) { y = bp - 2*P1W + 1;   x = 0; }
        else                     { y = bp - 2*P1W - (P1H-2) + 1; x = P1W - 1; }
        size_t o = (((size_t)n * P1H + y) * P1W + x) * C1 + c;
        f1hi[o] = 0; f1lo[o] = 0;
        return;
    }
    idx -= f1tot;
    if (idx < f2tot) {
        int c = idx & 63; int r = idx >> 6;
        int n = r / F2B; int bp = r % F2B;
        int y, x;
        if (bp < P2W)            { y = 0;        x = bp; }
        else if (bp < 2*P2W)     { y = P2H - 1;  x = bp - P2W; }
        else if (bp < 2*P2W + (P2H-2)) { y = bp - 2*P2W + 1;   x = 0; }
        else                     { y = bp - 2*P2W - (P2H-2) + 1; x = P2W - 1; }
        size_t o = (((size_t)n * P2H + y) * P2W + x) * C_ + c;
        f2hi[o] = 0; f2lo[o] = 0;
    }
}

// ---------------- geometry: A = K R Kinv, c = K t ----------------
__global__ void geom_kernel(const float* __restrict__ poses,
                            const float* __restrict__ Kmat,
                            float* __restrict__ geom) {
    int i = threadIdx.x;         // (b*V + v)
    if (i >= B_ * V_) return;
    int b = i / V_;
    const float* Kb = Kmat + b * 9;
    float k00=Kb[0],k01=Kb[1],k02=Kb[2];
    float k10=Kb[3],k11=Kb[4],k12=Kb[5];
    float k20=Kb[6],k21=Kb[7],k22=Kb[8];
    float det = k00*(k11*k22-k12*k21) - k01*(k10*k22-k12*k20) + k02*(k10*k21-k11*k20);
    float id = 1.0f / det;
    float ki[9];
    ki[0]=(k11*k22-k12*k21)*id; ki[1]=(k02*k21-k01*k22)*id; ki[2]=(k01*k12-k02*k11)*id;
    ki[3]=(k12*k20-k10*k22)*id; ki[4]=(k00*k22-k02*k20)*id; ki[5]=(k02*k10-k00*k12)*id;
    ki[6]=(k10*k21-k11*k20)*id; ki[7]=(k01*k20-k00*k21)*id; ki[8]=(k00*k11-k01*k10)*id;
    const float* P = poses + i * 16;
    float R[9] = {P[0],P[1],P[2], P[4],P[5],P[6], P[8],P[9],P[10]};
    float t[3] = {P[3],P[7],P[11]};
    float KR[9];
    for (int r = 0; r < 3; r++)
        for (int c = 0; c < 3; c++)
            KR[r*3+c] = Kb[r*3+0]*R[0*3+c] + Kb[r*3+1]*R[1*3+c] + Kb[r*3+2]*R[2*3+c];
    float* g = geom + i * 12;
    for (int r = 0; r < 3; r++)
        for (int c = 0; c < 3; c++)
            g[r*3+c] = KR[r*3+0]*ki[0*3+c] + KR[r*3+1]*ki[1*3+c] + KR[r*3+2]*ki[2*3+c];
    for (int r = 0; r < 3; r++)
        g[9+r] = Kb[r*3+0]*t[0] + Kb[r*3+1]*t[1] + Kb[r*3+2]*t[2];
}

// ---------------- conv1 MFMA: 3->32, 7x7, s2, p3, ReLU. out padded NHWC bf16 hi/lo
// wave: 16 px x 32 co; block 4 waves = 64 px; grid (1200, NIMG)
// K-groups g=(ci*7+ky) in [0,21), 8 shorts each (kx contiguous, j=7 zero-weight)
__global__ __launch_bounds__(256) void conv1_mfma(
        const ushort* __restrict__ ihi, const ushort* __restrict__ ilo,
        const ushort* __restrict__ w1p, const float* __restrict__ b1,
        ushort* __restrict__ f1hi, ushort* __restrict__ f1lo) {
    const int lane = threadIdx.x & 63;
    const int wv   = threadIdx.x >> 6;
    const int n    = blockIdx.y;
    const int px0  = blockIdx.x * 64 + wv * 16;
    const int p    = px0 + (lane & 15);      // A row
    const int y = p / W2, x = p % W2;
    const int kg = lane >> 4;
    const ushort* ih = ihi + (size_t)n * 3 * PIH * PIW;
    const ushort* il = ilo + (size_t)n * 3 * PIH * PIW;

    f32x4 acc[2] = {};
#pragma unroll
    for (int s = 0; s < 6; s++) {
        const int g = s * 4 + kg;
        short8 ahi = {}, alo = {};
        if (g < 21) {
            const int ci = g / 7, ky = g % 7;
            // physical input coords: iy = 2y + ky, ix = 2x (+j inside the 8-short load)
            const size_t off = ((size_t)(ci * PIH + 2 * y + ky)) * PIW + 2 * x;
            ahi = *reinterpret_cast<const short8*>(ih + off);   // 4B-aligned (x even*2B)
            alo = *reinterpret_cast<const short8*>(il + off);
        }
#pragma unroll
        for (int t = 0; t < 2; t++) {
            const int widx = ((t * 6 + s) * 64 + lane) * 8;
            short8 bhi = *reinterpret_cast<const short8*>(w1p + widx);
            short8 blo = *reinterpret_cast<const short8*>(w1p + 6144 + widx);
            acc[t] = __builtin_amdgcn_mfma_f32_16x16x32_bf16(ahi, bhi, acc[t], 0, 0, 0);
            acc[t] = __builtin_amdgcn_mfma_f32_16x16x32_bf16(ahi, blo, acc[t], 0, 0, 0);
            acc[t] = __builtin_amdgcn_mfma_f32_16x16x32_bf16(alo, bhi, acc[t], 0, 0, 0);
        }
    }
#pragma unroll
    for (int t = 0; t < 2; t++) {
        const int co = t * 16 + (lane & 15);
        const float bias = b1[co];
#pragma unroll
        for (int j = 0; j < 4; j++) {
            const int pr = px0 + kg * 4 + j;   // C row = (lane>>4)*4 + j
            const int oy = pr / W2, ox = pr % W2;
            float val = fmaxf(acc[t][j] + bias, 0.0f);
            __hip_bfloat16 h = __float2bfloat16(val);
            float hf = __bfloat162float(h);
            __hip_bfloat16 l = __float2bfloat16(val - hf);
            const size_t o = (((size_t)n * P1H + (oy + 1)) * P1W + (ox + 1)) * C1 + co;
            f1hi[o] = *reinterpret_cast<ushort*>(&h);
            f1lo[o] = *reinterpret_cast<ushort*>(&l);
        }
    }
}

// ---------------- conv2 MFMA: 32->64, 3x3, s2, p1, ReLU ----------------
__global__ __launch_bounds__(256) void conv2_mfma(
        const ushort* __restrict__ f1hi, const ushort* __restrict__ f1lo,
        const ushort* __restrict__ w2p, const float* __restrict__ b2,
        ushort* __restrict__ f2hi, ushort* __restrict__ f2lo) {
    const int lane = threadIdx.x & 63;
    const int wv   = threadIdx.x >> 6;
    const int n    = blockIdx.y;
    const int px0  = blockIdx.x * 64 + wv * 16;
    const int p    = px0 + (lane & 15);       // A row
    const int y = p / W4, x = p % W4;
    const int kg = lane >> 4;                 // 0..3
    const ushort* ihi = f1hi + (size_t)n * P1H * P1W * C1;
    const ushort* ilo = f1lo + (size_t)n * P1H * P1W * C1;

    f32x4 acc[4] = {};
#pragma unroll
    for (int s = 0; s < 9; s++) {
        const int ky = s / 3, kx = s % 3;
        const int off = ((2 * y + ky) * P1W + (2 * x + kx)) * C1 + kg * 8;
        short8 ahi = *reinterpret_cast<const short8*>(ihi + off);
        short8 alo = *reinterpret_cast<const short8*>(ilo + off);
#pragma unroll
        for (int t = 0; t < 4; t++) {
            const int widx = ((t * 9 + s) * 64 + lane) * 8;
            short8 bhi = *reinterpret_cast<const short8*>(w2p + widx);
            short8 blo = *reinterpret_cast<const short8*>(w2p + 18432 + widx);
            acc[t] = __builtin_amdgcn_mfma_f32_16x16x32_bf16(ahi, bhi, acc[t], 0, 0, 0);
            acc[t] = __builtin_amdgcn_mfma_f32_16x16x32_bf16(ahi, blo, acc[t], 0, 0, 0);
            acc[t] = __builtin_amdgcn_mfma_f32_16x16x32_bf16(alo, bhi, acc[t], 0, 0, 0);
        }
    }
    ushort* ohi = f2hi + (size_t)n * P2H * P2W * C_;
    ushort* olo = f2lo + (size_t)n * P2H * P2W * C_;
#pragma unroll
    for (int t = 0; t < 4; t++) {
        const int co = t * 16 + (lane & 15);
        const float bias = b2[co];
#pragma unroll
        for (int j = 0; j < 4; j++) {
            const int pr = px0 + kg * 4 + j;   // C row = (lane>>4)*4 + j
            const int yy = pr / W4, xx = pr % W4;
            float val = fmaxf(acc[t][j] + bias, 0.0f);
            __hip_bfloat16 h = __float2bfloat16(val);
            float hf = __bfloat162float(h);
            __hip_bfloat16 l = __float2bfloat16(val - hf);
            const size_t o = (((size_t)(yy + 1)) * P2W + (xx + 1)) * C_ + co;
            ohi[o] = *reinterpret_cast<ushort*>(&h);
            olo[o] = *reinterpret_cast<ushort*>(&l);
        }
    }
}

// ---------------- conv3 MFMA: 64->64, 3x3, s1, p1, no act. out NHWC fp32 ----
__global__ __launch_bounds__(256) void conv3_mfma(
        const ushort* __restrict__ f2hi, const ushort* __restrict__ f2lo,
        const ushort* __restrict__ w3p, const float* __restrict__ b3,
        float* __restrict__ f3) {
    const int lane = threadIdx.x & 63;
    const int wv   = threadIdx.x >> 6;
    const int n    = blockIdx.y;
    const int px0  = blockIdx.x * 64 + wv * 16;
    const int p    = px0 + (lane & 15);
    const int y = p / W4, x = p % W4;
    const int kg = lane >> 4;
    const ushort* ihi = f2hi + (size_t)n * P2H * P2W * C_;
    const ushort* ilo = f2lo + (size_t)n * P2H * P2W * C_;

    f32x4 acc[4] = {};
#pragma unroll
    for (int s = 0; s < 18; s++) {
        const int kyx = s >> 1;
        const int ky = kyx / 3, kx = kyx % 3;
        const int ci0 = (s & 1) * 32 + kg * 8;
        const int off = ((y + ky) * P2W + (x + kx)) * C_ + ci0;
        short8 ahi = *reinterpret_cast<const short8*>(ihi + off);
        short8 alo = *reinterpret_cast<const short8*>(ilo + off);
#pragma unroll
        for (int t = 0; t < 4; t++) {
            const int widx = ((t * 18 + s) * 64 + lane) * 8;
            short8 bhi = *reinterpret_cast<const short8*>(w3p + widx);
            short8 blo = *reinterpret_cast<const short8*>(w3p + 36864 + widx);
            acc[t] = __builtin_amdgcn_mfma_f32_16x16x32_bf16(ahi, bhi, acc[t], 0, 0, 0);
            acc[t] = __builtin_amdgcn_mfma_f32_16x16x32_bf16(ahi, blo, acc[t], 0, 0, 0);
            acc[t] = __builtin_amdgcn_mfma_f32_16x16x32_bf16(alo, bhi, acc[t], 0, 0, 0);
        }
    }
    float* op = f3 + (size_t)n * H4 * W4 * C_;
#pragma unroll
    for (int t = 0; t < 4; t++) {
        const int co = t * 16 + (lane & 15);
        const float bias = b3[co];
#pragma unroll
        for (int j = 0; j < 4; j++) {
            const int pr = px0 + kg * 4 + j;
            op[(size_t)pr * C_ + co] = acc[t][j] + bias;
        }
    }
}

// ---------------- warp + cost volume. one wave per (b,h,w) ----------------
__global__ void warpcost_kernel(const float* __restrict__ feat,  // NHWC, 10 imgs
                                const float* __restrict__ geom,
                                const float* __restrict__ dc,    // (B,D,H4,W4)
                                const int*   __restrict__ valid, // B*V ints
                                float* __restrict__ out) {
    const int wave = threadIdx.x >> 6;
    const int lane = threadIdx.x & 63;
    int pid = blockIdx.x * 4 + wave;  // 0 .. B*H4*W4-1
    int b = pid / (H4 * W4);
    int rem = pid % (H4 * W4);
    int h = rem / W4;
    int w = rem % W4;

    const float refc = feat[(((size_t)b * H4 + h) * W4 + w) * C_ + lane];

    float dep[D_];
#pragma unroll
    for (int d = 0; d < D_; d++)
        dep[d] = dc[(((size_t)b * D_ + d) * H4 + h) * W4 + w];

    float accv[D_] = {0.f, 0.f, 0.f, 0.f, 0.f};
    float den[D_]  = {0.f, 0.f, 0.f, 0.f, 0.f};

    for (int v = 0; v < V_; v++) {
        if (!valid[b * V_ + v]) continue;
        const float* g = geom + (b * V_ + v) * 12;
        float rx = g[0] * w + g[1] * h + g[2];
        float ry = g[3] * w + g[4] * h + g[5];
        float rz = g[6] * w + g[7] * h + g[8];
        float c0 = g[9], c1 = g[10], c2 = g[11];
        const float* fimg = feat + (size_t)(B_ + b * V_ + v) * H4 * W4 * C_;
#pragma unroll
        for (int d = 0; d < D_; d++) {
            float px = dep[d] * rx + c0;
            float py = dep[d] * ry + c1;
            float pz = dep[d] * rz + c2;
            bool zok = pz > 0.001f;
            float zc = fmaxf(pz, 0.001f);
            float u  = px / zc;
            float vv = py / zc;
            bool inb = (u >= 0.f) && (u <= (float)(W4 - 1)) &&
                       (vv >= 0.f) && (vv <= (float)(H4 - 1));
            if (zok && inb) {   // wave-uniform branch
                float u0f = floorf(u), v0f = floorf(vv);
                float du = u - u0f, dv = vv - v0f;
                int u0 = (int)u0f, v0 = (int)v0f;
                int u1 = min(u0 + 1, W4 - 1), v1 = min(v0 + 1, H4 - 1);
                const float* r00 = fimg + ((size_t)v0 * W4 + u0) * C_;
                const float* r01 = fimg + ((size_t)v0 * W4 + u1) * C_;
                const float* r10 = fimg + ((size_t)v1 * W4 + u0) * C_;
                const float* r11 = fimg + ((size_t)v1 * W4 + u1) * C_;
                float f00 = r00[lane], f01 = r01[lane];
                float f10 = r10[lane], f11 = r11[lane];
                float wa = (1.f - du) * (1.f - dv);
                float wb = du * (1.f - dv);
                float wc = (1.f - du) * dv;
                float wd = du * dv;
                accv[d] += f00 * wa + f01 * wb + f10 * wc + f11 * wd;
                den[d]  += 1.f;
            }
        }
    }

#pragma unroll
    for (int d = 0; d < D_; d++) {
        float s = refc * accv[d];
        for (int off = 32; off > 0; off >>= 1) s += __shfl_xor(s, off, 64);
        if (lane == 0) {
            out[(((size_t)b * D_ + d) * H4 + h) * W4 + w] =
                (s * (1.0f / (float)C_)) / fmaxf(den[d], 1.0f);
        }
    }
}

extern "C" void kernel_launch(void* const* d_in, const int* in_sizes, int n_in,
                              void* d_out, int out_size, void* d_ws, size_t ws_size,
                              hipStream_t stream) {
    const float* ref_img  = (const float*)d_in[0];
    const float* ngh_img  = (const float*)d_in[1];
    const float* poses    = (const float*)d_in[2];
    const int*   is_valid = (const int*)  d_in[3];
    const float* K        = (const float*)d_in[4];
    const float* dc       = (const float*)d_in[5];
    const float* w1 = (const float*)d_in[6];
    const float* b1 = (const float*)d_in[7];
    const float* w2 = (const float*)d_in[8];
    const float* b2 = (const float*)d_in[9];
    const float* w3 = (const float*)d_in[10];
    const float* b3 = (const float*)d_in[11];
    float* out = (float*)d_out;

    float* ws = (float*)d_ws;
    ushort* f1hi = (ushort*)(ws + OFF_F1HI);
    ushort* f1lo = (ushort*)(ws + OFF_F1LO);
    ushort* f2hi = (ushort*)(ws + OFF_F2HI);
    ushort* f2lo = (ushort*)(ws + OFF_F2LO);
    ushort* inhi = (ushort*)(ws + OFF_INHI);  // aliases f2 region (dead after conv1)
    ushort* inlo = (ushort*)(ws + OFF_INLO);
    float*  f3   = ws + OFF_F3;               // overlaps f1 (dead after conv2)
    float*  geom = ws + OFF_GEOM;
    ushort* w1p  = (ushort*)(ws + OFF_W1P);
    ushort* w2p  = (ushort*)(ws + OFF_W2P);
    ushort* w3p  = (ushort*)(ws + OFF_W3P);

    geom_kernel<<<1, 64, 0, stream>>>(poses, K, geom);
    packw1_kernel<<<24, 256, 0, stream>>>(w1, w1p);
    packw_kernel<<<(4*9*64*8 + 255)/256, 256, 0, stream>>>(w2, w2p, C1, 9, 18432);
    packw_kernel<<<(4*18*64*8 + 255)/256, 256, 0, stream>>>(w3, w3p, C_, 18, 36864);
    packin_kernel<<<(NIMG*3*PIH*PIW + 255)/256, 256, 0, stream>>>(ref_img, ngh_img, inhi, inlo);

    conv1_mfma<<<dim3(H2*W2/64, NIMG), 256, 0, stream>>>(inhi, inlo, w1p, b1, f1hi, f1lo);
    {   // zero pad borders: f1 before conv2 reads them; f2 after inp (alias) is dead
        const int ztot = NIMG*(2*P1W + 2*(P1H-2))*C1 + NIMG*(2*P2W + 2*(P2H-2))*C_;
        zerob_kernel<<<(ztot + 255)/256, 256, 0, stream>>>(f1hi, f1lo, f2hi, f2lo);
    }
    conv2_mfma<<<dim3(H4*W4/64, NIMG), 256, 0, stream>>>(f1hi, f1lo, w2p, b2, f2hi, f2lo);
    conv3_mfma<<<dim3(H4*W4/64, NIMG), 256, 0, stream>>>(f2hi, f2lo, w3p, b3, f3);

    warpcost_kernel<<<(B_*H4*W4)/4, 256, 0, stream>>>(f3, geom, dc, is_valid, out);
}

// Round 8
// 437.984 us; speedup vs baseline: 1.6682x; 1.0355x over previous
//
#include <hip/hip_runtime.h>
#include <hip/hip_bf16.h>

// Problem constants
#define B_  2
#define V_  4
#define Hin 480
#define Win 640
#define H2  240   // after conv1 (s2)
#define W2  320
#define H4  120   // after conv2 (s2)
#define W4  160
#define C1  32
#define C_  64
#define D_  5
#define NIMG 10  // B + B*V
#define HW4 (H4*W4)

// padded feature dims
#define P1H 242
#define P1W 322
#define P2H 122
#define P2W 162
// padded raw-input dims (for conv1 MFMA)
#define PIH 486
#define PIW 646

typedef __attribute__((ext_vector_type(8))) short short8;
typedef __attribute__((ext_vector_type(4))) float f32x4;

// ---------------- workspace layout (float offsets) ----------------
// f1hi (bf16 [10][242][322][32]) @ 0          : 12,467,840 floats
// f1lo                           @ 12,467,840 : 12,467,840
// f2hi (bf16 [10][122][162][64]) @ 24,935,680 :  6,324,480
// f2lo                           @ 31,260,160 :  6,324,480
// inp_hi (bf16 [10][3][486][646])@ 24,935,680 (ALIAS f2hi region; dead after conv1)
// inp_lo                         @ 29,645,504
// f3   (fp32 NHWC 10x19200x64)   @ 0 (overlaps f1hi; f1 dead after conv2)
// sampW (f32x4 [768000])         @ 12,467,840 (ALIAS f1lo; f1 dead after conv2)
// sampM (int   [768000])         @ 15,539,840
// geom @ 37,584,640 ; w1p @ 37,584,736 ; w2p @ 37,590,880 ; w3p @ 37,609,312
#define OFF_F1HI 0
#define OFF_F1LO 12467840
#define OFF_F2HI 24935680
#define OFF_F2LO 31260160
#define OFF_INHI 24935680
#define OFF_INLO 29645504
#define OFF_F3   0
#define OFF_SAMPW 12467840
#define OFF_SAMPM 15539840
#define OFF_GEOM 37584640
#define OFF_W1P  37584736   // ushort[2*6144]: hi then lo
#define OFF_W2P  37590880   // ushort[2*18432]: hi then lo
#define OFF_W3P  37609312   // ushort[2*36864]: hi then lo

// ---------------- pack conv2/conv3 weights into MFMA B-fragment order ----
__global__ void packw_kernel(const float* __restrict__ w, ushort* __restrict__ dst,
                             int CI, int NK, int lo_off) {
    int idx = blockIdx.x * 256 + threadIdx.x;
    int total = 4 * NK * 64 * 8;
    if (idx >= total) return;
    int j = idx & 7;
    int lane = (idx >> 3) & 63;
    int s = (idx >> 9) % NK;
    int t = idx / (NK * 512);
    int k = s * 32 + (lane >> 4) * 8 + j;
    int co = t * 16 + (lane & 15);
    int kyx = k / CI;
    int ci  = k % CI;
    int ky = kyx / 3, kx = kyx % 3;
    float val = w[((co * CI + ci) * 3 + ky) * 3 + kx];
    __hip_bfloat16 h = __float2bfloat16(val);
    float hf = __bfloat162float(h);
    __hip_bfloat16 l = __float2bfloat16(val - hf);
    dst[idx]          = *reinterpret_cast<ushort*>(&h);
    dst[lo_off + idx] = *reinterpret_cast<ushort*>(&l);
}

// ---------------- pack conv1 weights ----
__global__ void packw1_kernel(const float* __restrict__ w, ushort* __restrict__ dst) {
    int idx = blockIdx.x * 256 + threadIdx.x;
    if (idx >= 6144) return;
    int j = idx & 7;
    int lane = (idx >> 3) & 63;
    int s = (idx >> 9) % 6;
    int t = idx / 3072;
    int g = s * 4 + (lane >> 4);
    int co = t * 16 + (lane & 15);
    float val = 0.0f;
    if (g < 21 && j < 7) {
        int ci = g / 7, ky = g % 7;
        val = w[((co * 3 + ci) * 7 + ky) * 7 + j];
    }
    __hip_bfloat16 h = __float2bfloat16(val);
    float hf = __bfloat162float(h);
    __hip_bfloat16 l = __float2bfloat16(val - hf);
    dst[idx]        = *reinterpret_cast<ushort*>(&h);
    dst[6144 + idx] = *reinterpret_cast<ushort*>(&l);
}

// ---------------- pack raw images to padded NCHW bf16 hi/lo ----------------
__global__ void packin_kernel(const float* __restrict__ ref, const float* __restrict__ ngh,
                              ushort* __restrict__ ihi, ushort* __restrict__ ilo) {
    int idx = blockIdx.x * 256 + threadIdx.x;
    const int tot = NIMG * 3 * PIH * PIW;
    if (idx >= tot) return;
    int x = idx % PIW;
    int r = idx / PIW;
    int y = r % PIH;
    int rc = r / PIH;
    int ci = rc % 3;
    int n  = rc / 3;
    float val = 0.0f;
    int lx = x - 3, ly = y - 3;
    if (lx >= 0 && lx < Win && ly >= 0 && ly < Hin) {
        const float* img = (n < B_) ? (ref + ((size_t)n * 3 + ci) * Hin * Win)
                                    : (ngh + ((size_t)(n - B_) * 3 + ci) * Hin * Win);
        val = img[(size_t)ly * Win + lx];
    }
    __hip_bfloat16 h = __float2bfloat16(val);
    float hf = __bfloat162float(h);
    __hip_bfloat16 l = __float2bfloat16(val - hf);
    ihi[idx] = *reinterpret_cast<ushort*>(&h);
    ilo[idx] = *reinterpret_cast<ushort*>(&l);
}

// ---------------- zero padded-border cells of f1 and f2 ----------------
__global__ void zerob_kernel(ushort* __restrict__ f1hi, ushort* __restrict__ f1lo,
                             ushort* __restrict__ f2hi, ushort* __restrict__ f2lo) {
    const int F1B = 2 * P1W + 2 * (P1H - 2);
    const int F2B = 2 * P2W + 2 * (P2H - 2);
    const int f1tot = NIMG * F1B * C1;
    const int f2tot = NIMG * F2B * C_;
    int idx = blockIdx.x * 256 + threadIdx.x;
    if (idx < f1tot) {
        int c = idx & 31; int r = idx >> 5;
        int n = r / F1B; int bp = r % F1B;
        int y, x;
        if (bp < P1W)            { y = 0;        x = bp; }
        else if (bp < 2*P1W)     { y = P1H - 1;  x = bp - P1W; }
        else if (bp < 2*P1W + (P1H-2)) { y = bp - 2*P1W + 1;   x = 0; }
        else                     { y = bp - 2*P1W - (P1H-2) + 1; x = P1W - 1; }
        size_t o = (((size_t)n * P1H + y) * P1W + x) * C1 + c;
        f1hi[o] = 0; f1lo[o] = 0;
        return;
    }
    idx -= f1tot;
    if (idx < f2tot) {
        int c = idx & 63; int r = idx >> 6;
        int n = r / F2B; int bp = r % F2B;
        int y, x;
        if (bp < P2W)            { y = 0;        x = bp; }
        else if (bp < 2*P2W)     { y = P2H - 1;  x = bp - P2W; }
        else if (bp < 2*P2W + (P2H-2)) { y = bp - 2*P2W + 1;   x = 0; }
        else                     { y = bp - 2*P2W - (P2H-2) + 1; x = P2W - 1; }
        size_t o = (((size_t)n * P2H + y) * P2W + x) * C_ + c;
        f2hi[o] = 0; f2lo[o] = 0;
    }
}

// ---------------- geometry: A = K R Kinv, c = K t ----------------
__global__ void geom_kernel(const float* __restrict__ poses,
                            const float* __restrict__ Kmat,
                            float* __restrict__ geom) {
    int i = threadIdx.x;         // (b*V + v)
    if (i >= B_ * V_) return;
    int b = i / V_;
    const float* Kb = Kmat + b * 9;
    float k00=Kb[0],k01=Kb[1],k02=Kb[2];
    float k10=Kb[3],k11=Kb[4],k12=Kb[5];
    float k20=Kb[6],k21=Kb[7],k22=Kb[8];
    float det = k00*(k11*k22-k12*k21) - k01*(k10*k22-k12*k20) + k02*(k10*k21-k11*k20);
    float id = 1.0f / det;
    float ki[9];
    ki[0]=(k11*k22-k12*k21)*id; ki[1]=(k02*k21-k01*k22)*id; ki[2]=(k01*k12-k02*k11)*id;
    ki[3]=(k12*k20-k10*k22)*id; ki[4]=(k00*k22-k02*k20)*id; ki[5]=(k02*k10-k00*k12)*id;
    ki[6]=(k10*k21-k11*k20)*id; ki[7]=(k01*k20-k00*k21)*id; ki[8]=(k00*k11-k01*k10)*id;
    const float* P = poses + i * 16;
    float R[9] = {P[0],P[1],P[2], P[4],P[5],P[6], P[8],P[9],P[10]};
    float t[3] = {P[3],P[7],P[11]};
    float KR[9];
    for (int r = 0; r < 3; r++)
        for (int c = 0; c < 3; c++)
            KR[r*3+c] = Kb[r*3+0]*R[0*3+c] + Kb[r*3+1]*R[1*3+c] + Kb[r*3+2]*R[2*3+c];
    float* g = geom + i * 12;
    for (int r = 0; r < 3; r++)
        for (int c = 0; c < 3; c++)
            g[r*3+c] = KR[r*3+0]*ki[0*3+c] + KR[r*3+1]*ki[1*3+c] + KR[r*3+2]*ki[2*3+c];
    for (int r = 0; r < 3; r++)
        g[9+r] = Kb[r*3+0]*t[0] + Kb[r*3+1]*t[1] + Kb[r*3+2]*t[2];
}

// ---------------- conv1 MFMA: 3->32, 7x7, s2, p3, ReLU ----------------
__global__ __launch_bounds__(256) void conv1_mfma(
        const ushort* __restrict__ ihi, const ushort* __restrict__ ilo,
        const ushort* __restrict__ w1p, const float* __restrict__ b1,
        ushort* __restrict__ f1hi, ushort* __restrict__ f1lo) {
    const int lane = threadIdx.x & 63;
    const int wv   = threadIdx.x >> 6;
    const int n    = blockIdx.y;
    const int px0  = blockIdx.x * 64 + wv * 16;
    const int p    = px0 + (lane & 15);      // A row
    const int y = p / W2, x = p % W2;
    const int kg = lane >> 4;
    const ushort* ih = ihi + (size_t)n * 3 * PIH * PIW;
    const ushort* il = ilo + (size_t)n * 3 * PIH * PIW;

    f32x4 acc[2] = {};
#pragma unroll
    for (int s = 0; s < 6; s++) {
        const int g = s * 4 + kg;
        short8 ahi = {}, alo = {};
        if (g < 21) {
            const int ci = g / 7, ky = g % 7;
            const size_t off = ((size_t)(ci * PIH + 2 * y + ky)) * PIW + 2 * x;
            ahi = *reinterpret_cast<const short8*>(ih + off);
            alo = *reinterpret_cast<const short8*>(il + off);
        }
#pragma unroll
        for (int t = 0; t < 2; t++) {
            const int widx = ((t * 6 + s) * 64 + lane) * 8;
            short8 bhi = *reinterpret_cast<const short8*>(w1p + widx);
            short8 blo = *reinterpret_cast<const short8*>(w1p + 6144 + widx);
            acc[t] = __builtin_amdgcn_mfma_f32_16x16x32_bf16(ahi, bhi, acc[t], 0, 0, 0);
            acc[t] = __builtin_amdgcn_mfma_f32_16x16x32_bf16(ahi, blo, acc[t], 0, 0, 0);
            acc[t] = __builtin_amdgcn_mfma_f32_16x16x32_bf16(alo, bhi, acc[t], 0, 0, 0);
        }
    }
#pragma unroll
    for (int t = 0; t < 2; t++) {
        const int co = t * 16 + (lane & 15);
        const float bias = b1[co];
#pragma unroll
        for (int j = 0; j < 4; j++) {
            const int pr = px0 + kg * 4 + j;
            const int oy = pr / W2, ox = pr % W2;
            float val = fmaxf(acc[t][j] + bias, 0.0f);
            __hip_bfloat16 h = __float2bfloat16(val);
            float hf = __bfloat162float(h);
            __hip_bfloat16 l = __float2bfloat16(val - hf);
            const size_t o = (((size_t)n * P1H + (oy + 1)) * P1W + (ox + 1)) * C1 + co;
            f1hi[o] = *reinterpret_cast<ushort*>(&h);
            f1lo[o] = *reinterpret_cast<ushort*>(&l);
        }
    }
}

// ---------------- conv2 MFMA: 32->64, 3x3, s2, p1, ReLU ----------------
__global__ __launch_bounds__(256) void conv2_mfma(
        const ushort* __restrict__ f1hi, const ushort* __restrict__ f1lo,
        const ushort* __restrict__ w2p, const float* __restrict__ b2,
        ushort* __restrict__ f2hi, ushort* __restrict__ f2lo) {
    const int lane = threadIdx.x & 63;
    const int wv   = threadIdx.x >> 6;
    const int n    = blockIdx.y;
    const int px0  = blockIdx.x * 64 + wv * 16;
    const int p    = px0 + (lane & 15);       // A row
    const int y = p / W4, x = p % W4;
    const int kg = lane >> 4;                 // 0..3
    const ushort* ihi = f1hi + (size_t)n * P1H * P1W * C1;
    const ushort* ilo = f1lo + (size_t)n * P1H * P1W * C1;

    f32x4 acc[4] = {};
#pragma unroll
    for (int s = 0; s < 9; s++) {
        const int ky = s / 3, kx = s % 3;
        const int off = ((2 * y + ky) * P1W + (2 * x + kx)) * C1 + kg * 8;
        short8 ahi = *reinterpret_cast<const short8*>(ihi + off);
        short8 alo = *reinterpret_cast<const short8*>(ilo + off);
#pragma unroll
        for (int t = 0; t < 4; t++) {
            const int widx = ((t * 9 + s) * 64 + lane) * 8;
            short8 bhi = *reinterpret_cast<const short8*>(w2p + widx);
            short8 blo = *reinterpret_cast<const short8*>(w2p + 18432 + widx);
            acc[t] = __builtin_amdgcn_mfma_f32_16x16x32_bf16(ahi, bhi, acc[t], 0, 0, 0);
            acc[t] = __builtin_amdgcn_mfma_f32_16x16x32_bf16(ahi, blo, acc[t], 0, 0, 0);
            acc[t] = __builtin_amdgcn_mfma_f32_16x16x32_bf16(alo, bhi, acc[t], 0, 0, 0);
        }
    }
    ushort* ohi = f2hi + (size_t)n * P2H * P2W * C_;
    ushort* olo = f2lo + (size_t)n * P2H * P2W * C_;
#pragma unroll
    for (int t = 0; t < 4; t++) {
        const int co = t * 16 + (lane & 15);
        const float bias = b2[co];
#pragma unroll
        for (int j = 0; j < 4; j++) {
            const int pr = px0 + kg * 4 + j;
            const int yy = pr / W4, xx = pr % W4;
            float val = fmaxf(acc[t][j] + bias, 0.0f);
            __hip_bfloat16 h = __float2bfloat16(val);
            float hf = __bfloat162float(h);
            __hip_bfloat16 l = __float2bfloat16(val - hf);
            const size_t o = (((size_t)(yy + 1)) * P2W + (xx + 1)) * C_ + co;
            ohi[o] = *reinterpret_cast<ushort*>(&h);
            olo[o] = *reinterpret_cast<ushort*>(&l);
        }
    }
}

// ---------------- conv3 MFMA: 64->64, 3x3, s1, p1, no act. out NHWC fp32 ----
__global__ __launch_bounds__(256) void conv3_mfma(
        const ushort* __restrict__ f2hi, const ushort* __restrict__ f2lo,
        const ushort* __restrict__ w3p, const float* __restrict__ b3,
        float* __restrict__ f3) {
    const int lane = threadIdx.x & 63;
    const int wv   = threadIdx.x >> 6;
    const int n    = blockIdx.y;
    const int px0  = blockIdx.x * 64 + wv * 16;
    const int p    = px0 + (lane & 15);
    const int y = p / W4, x = p % W4;
    const int kg = lane >> 4;
    const ushort* ihi = f2hi + (size_t)n * P2H * P2W * C_;
    const ushort* ilo = f2lo + (size_t)n * P2H * P2W * C_;

    f32x4 acc[4] = {};
#pragma unroll
    for (int s = 0; s < 18; s++) {
        const int kyx = s >> 1;
        const int ky = kyx / 3, kx = kyx % 3;
        const int ci0 = (s & 1) * 32 + kg * 8;
        const int off = ((y + ky) * P2W + (x + kx)) * C_ + ci0;
        short8 ahi = *reinterpret_cast<const short8*>(ihi + off);
        short8 alo = *reinterpret_cast<const short8*>(ilo + off);
#pragma unroll
        for (int t = 0; t < 4; t++) {
            const int widx = ((t * 18 + s) * 64 + lane) * 8;
            short8 bhi = *reinterpret_cast<const short8*>(w3p + widx);
            short8 blo = *reinterpret_cast<const short8*>(w3p + 36864 + widx);
            acc[t] = __builtin_amdgcn_mfma_f32_16x16x32_bf16(ahi, bhi, acc[t], 0, 0, 0);
            acc[t] = __builtin_amdgcn_mfma_f32_16x16x32_bf16(ahi, blo, acc[t], 0, 0, 0);
            acc[t] = __builtin_amdgcn_mfma_f32_16x16x32_bf16(alo, bhi, acc[t], 0, 0, 0);
        }
    }
    float* op = f3 + (size_t)n * H4 * W4 * C_;
#pragma unroll
    for (int t = 0; t < 4; t++) {
        const int co = t * 16 + (lane & 15);
        const float bias = b3[co];
#pragma unroll
        for (int j = 0; j < 4; j++) {
            const int pr = px0 + kg * 4 + j;
            op[(size_t)pr * C_ + co] = acc[t][j] + bias;
        }
    }
}

// ---------------- sample geometry: one thread per (b,v,d,h,w) ----------------
// record: sw = {w00,w01,w10,w11}; sm = off00 | off10<<15 | mask<<30
__global__ void samp_kernel(const float* __restrict__ geom,
                            const float* __restrict__ dc,
                            const int*   __restrict__ valid,
                            f32x4* __restrict__ sw, int* __restrict__ sm) {
    int idx = blockIdx.x * 256 + threadIdx.x;
    if (idx >= B_ * V_ * D_ * HW4) return;
    int hw = idx % HW4;
    int r  = idx / HW4;
    int d = r % D_;  r /= D_;
    int v = r % V_;  int b = r / V_;
    int h = hw / W4, w = hw % W4;

    float dep = dc[((size_t)(b * D_ + d)) * HW4 + hw];
    const float* g = geom + (b * V_ + v) * 12;
    float px = dep * (g[0] * w + g[1] * h + g[2]) + g[9];
    float py = dep * (g[3] * w + g[4] * h + g[5]) + g[10];
    float pz = dep * (g[6] * w + g[7] * h + g[8]) + g[11];
    bool zok = pz > 0.001f;
    float zc = fmaxf(pz, 0.001f);
    float u  = px / zc;
    float vv = py / zc;
    bool inb = (u >= 0.f) && (u <= (float)(W4 - 1)) &&
               (vv >= 0.f) && (vv <= (float)(H4 - 1));
    bool m = zok && inb && (valid[b * V_ + v] != 0);

    f32x4 wgt = {0.f, 0.f, 0.f, 0.f};
    int rec = 0;
    if (m) {
        float u0f = floorf(u), v0f = floorf(vv);
        float du = u - u0f, dv = vv - v0f;
        int u0 = (int)u0f, v0 = (int)v0f;
        int off00 = v0 * W4 + u0;
        int off10 = min(v0 + 1, H4 - 1) * W4 + u0;
        wgt[0] = (1.f - du) * (1.f - dv);
        wgt[1] = du * (1.f - dv);
        wgt[2] = (1.f - du) * dv;
        wgt[3] = du * dv;
        rec = off00 | (off10 << 15) | (1 << 30);
    }
    sw[idx] = wgt;
    sm[idx] = rec;
}

// ---------------- warp + cost volume. one wave per (b,h,w) ----------------
__global__ __launch_bounds__(256) void warpcost_kernel(
        const float* __restrict__ feat,   // NHWC, 10 imgs
        const f32x4* __restrict__ sw, const int* __restrict__ sm,
        float* __restrict__ out) {
    const int wave = threadIdx.x >> 6;
    const int lane = threadIdx.x & 63;
    int pid = blockIdx.x * 4 + wave;  // 0 .. B*HW4-1
    int b = pid / HW4;
    int hw = pid % HW4;

    const float refc = feat[((size_t)b * HW4 + hw) * C_ + lane];

    float accv[D_] = {0.f, 0.f, 0.f, 0.f, 0.f};
    float den[D_]  = {0.f, 0.f, 0.f, 0.f, 0.f};

#pragma unroll
    for (int v = 0; v < V_; v++) {
        const float* fimg = feat + (size_t)(B_ + b * V_ + v) * HW4 * C_;
        const int rbase = ((b * V_ + v) * D_) * HW4 + hw;
#pragma unroll
        for (int d = 0; d < D_; d++) {
            int rec  = sm[rbase + d * HW4];
            f32x4 wv = sw[rbase + d * HW4];
            int off00 = rec & 0x7FFF;
            int off10 = (rec >> 15) & 0x7FFF;
            const float* p0 = fimg + (size_t)off00 * C_ + lane;
            const float* p1 = fimg + (size_t)off10 * C_ + lane;
            accv[d] += p0[0] * wv[0] + p0[C_] * wv[1] + p1[0] * wv[2] + p1[C_] * wv[3];
            den[d]  += (float)((rec >> 30) & 1);
        }
    }

#pragma unroll
    for (int d = 0; d < D_; d++) {
        float s = refc * accv[d];
        for (int off = 32; off > 0; off >>= 1) s += __shfl_xor(s, off, 64);
        if (lane == 0) {
            out[((size_t)b * D_ + d) * HW4 + hw] =
                (s * (1.0f / (float)C_)) / fmaxf(den[d], 1.0f);
        }
    }
}

extern "C" void kernel_launch(void* const* d_in, const int* in_sizes, int n_in,
                              void* d_out, int out_size, void* d_ws, size_t ws_size,
                              hipStream_t stream) {
    const float* ref_img  = (const float*)d_in[0];
    const float* ngh_img  = (const float*)d_in[1];
    const float* poses    = (const float*)d_in[2];
    const int*   is_valid = (const int*)  d_in[3];
    const float* K        = (const float*)d_in[4];
    const float* dc       = (const float*)d_in[5];
    const float* w1 = (const float*)d_in[6];
    const float* b1 = (const float*)d_in[7];
    const float* w2 = (const float*)d_in[8];
    const float* b2 = (const float*)d_in[9];
    const float* w3 = (const float*)d_in[10];
    const float* b3 = (const float*)d_in[11];
    float* out = (float*)d_out;

    float* ws = (float*)d_ws;
    ushort* f1hi = (ushort*)(ws + OFF_F1HI);
    ushort* f1lo = (ushort*)(ws + OFF_F1LO);
    ushort* f2hi = (ushort*)(ws + OFF_F2HI);
    ushort* f2lo = (ushort*)(ws + OFF_F2LO);
    ushort* inhi = (ushort*)(ws + OFF_INHI);  // aliases f2 region (dead after conv1)
    ushort* inlo = (ushort*)(ws + OFF_INLO);
    float*  f3   = ws + OFF_F3;               // overlaps f1hi (dead after conv2)
    f32x4*  sw   = (f32x4*)(ws + OFF_SAMPW);  // aliases f1lo (dead after conv2)
    int*    sm   = (int*)  (ws + OFF_SAMPM);
    float*  geom = ws + OFF_GEOM;
    ushort* w1p  = (ushort*)(ws + OFF_W1P);
    ushort* w2p  = (ushort*)(ws + OFF_W2P);
    ushort* w3p  = (ushort*)(ws + OFF_W3P);

    geom_kernel<<<1, 64, 0, stream>>>(poses, K, geom);
    packw1_kernel<<<24, 256, 0, stream>>>(w1, w1p);
    packw_kernel<<<(4*9*64*8 + 255)/256, 256, 0, stream>>>(w2, w2p, C1, 9, 18432);
    packw_kernel<<<(4*18*64*8 + 255)/256, 256, 0, stream>>>(w3, w3p, C_, 18, 36864);
    packin_kernel<<<(NIMG*3*PIH*PIW + 255)/256, 256, 0, stream>>>(ref_img, ngh_img, inhi, inlo);

    conv1_mfma<<<dim3(H2*W2/64, NIMG), 256, 0, stream>>>(inhi, inlo, w1p, b1, f1hi, f1lo);
    {
        const int ztot = NIMG*(2*P1W + 2*(P1H-2))*C1 + NIMG*(2*P2W + 2*(P2H-2))*C_;
        zerob_kernel<<<(ztot + 255)/256, 256, 0, stream>>>(f1hi, f1lo, f2hi, f2lo);
    }
    conv2_mfma<<<dim3(H4*W4/64, NIMG), 256, 0, stream>>>(f1hi, f1lo, w2p, b2, f2hi, f2lo);
    // samp writes into the f1lo alias -> must follow conv2 (stream-ordered)
    samp_kernel<<<(B_*V_*D_*HW4 + 255)/256, 256, 0, stream>>>(geom, dc, is_valid, sw, sm);
    conv3_mfma<<<dim3(H4*W4/64, NIMG), 256, 0, stream>>>(f2hi, f2lo, w3p, b3, f3);

    warpcost_kernel<<<(B_*HW4)/4, 256, 0, stream>>>(f3, sw, sm, out);
}

// Round 9
// 407.513 us; speedup vs baseline: 1.7929x; 1.0748x over previous
//
#include <hip/hip_runtime.h>
#include <hip/hip_bf16.h>

// Problem constants
#define B_  2
#define V_  4
#define Hin 480
#define Win 640
#define H2  240   // after conv1 (s2)
#define W2  320
#define H4  120   // after conv2 (s2)
#define W4  160
#define C1  32
#define C_  64
#define D_  5
#define NIMG 10  // B + B*V
#define HW4 (H4*W4)

// padded feature dims
#define P1H 242
#define P1W 322
#define P2H 122
#define P2W 162
// padded raw-input dims (for conv1 MFMA)
#define PIH 486
#define PIW 646

typedef __attribute__((ext_vector_type(8))) short short8;
typedef __attribute__((ext_vector_type(4))) float f32x4;

// ---------------- workspace layout (float offsets) ----------------
#define OFF_F1HI 0
#define OFF_F1LO 12467840
#define OFF_F2HI 24935680
#define OFF_F2LO 31260160
#define OFF_INHI 24935680
#define OFF_INLO 29645504
#define OFF_F3   0
#define OFF_SAMPW 12467840
#define OFF_SAMPM 15539840
#define OFF_GEOM 37584640
#define OFF_W1P  37584736   // ushort[2*6144]: hi then lo
#define OFF_W2P  37590880   // ushort[2*18432]: hi then lo
#define OFF_W3P  37609312   // ushort[2*36864]: hi then lo

// bijective XCD-aware block swizzle (m204): consecutive output tiles -> same XCD
__device__ __forceinline__ int swz8(int o, int n) {
    int x = o & 7, i = o >> 3, q = n >> 3, r = n & 7;
    return (x < r) ? (x * (q + 1) + i) : (r * (q + 1) + (x - r) * q + i);
}

// ---------------- pack conv2/conv3 weights into MFMA B-fragment order ----
__global__ void packw_kernel(const float* __restrict__ w, ushort* __restrict__ dst,
                             int CI, int NK, int lo_off) {
    int idx = blockIdx.x * 256 + threadIdx.x;
    int total = 4 * NK * 64 * 8;
    if (idx >= total) return;
    int j = idx & 7;
    int lane = (idx >> 3) & 63;
    int s = (idx >> 9) % NK;
    int t = idx / (NK * 512);
    int k = s * 32 + (lane >> 4) * 8 + j;
    int co = t * 16 + (lane & 15);
    int kyx = k / CI;
    int ci  = k % CI;
    int ky = kyx / 3, kx = kyx % 3;
    float val = w[((co * CI + ci) * 3 + ky) * 3 + kx];
    __hip_bfloat16 h = __float2bfloat16(val);
    float hf = __bfloat162float(h);
    __hip_bfloat16 l = __float2bfloat16(val - hf);
    dst[idx]          = *reinterpret_cast<ushort*>(&h);
    dst[lo_off + idx] = *reinterpret_cast<ushort*>(&l);
}

// ---------------- pack conv1 weights ----
__global__ void packw1_kernel(const float* __restrict__ w, ushort* __restrict__ dst) {
    int idx = blockIdx.x * 256 + threadIdx.x;
    if (idx >= 6144) return;
    int j = idx & 7;
    int lane = (idx >> 3) & 63;
    int s = (idx >> 9) % 6;
    int t = idx / 3072;
    int g = s * 4 + (lane >> 4);
    int co = t * 16 + (lane & 15);
    float val = 0.0f;
    if (g < 21 && j < 7) {
        int ci = g / 7, ky = g % 7;
        val = w[((co * 3 + ci) * 7 + ky) * 7 + j];
    }
    __hip_bfloat16 h = __float2bfloat16(val);
    float hf = __bfloat162float(h);
    __hip_bfloat16 l = __float2bfloat16(val - hf);
    dst[idx]        = *reinterpret_cast<ushort*>(&h);
    dst[6144 + idx] = *reinterpret_cast<ushort*>(&l);
}

// ---------------- pack raw images to padded NCHW bf16 hi/lo ----------------
__global__ void packin_kernel(const float* __restrict__ ref, const float* __restrict__ ngh,
                              ushort* __restrict__ ihi, ushort* __restrict__ ilo) {
    int idx = blockIdx.x * 256 + threadIdx.x;
    const int tot = NIMG * 3 * PIH * PIW;
    if (idx >= tot) return;
    int x = idx % PIW;
    int r = idx / PIW;
    int y = r % PIH;
    int rc = r / PIH;
    int ci = rc % 3;
    int n  = rc / 3;
    float val = 0.0f;
    int lx = x - 3, ly = y - 3;
    if (lx >= 0 && lx < Win && ly >= 0 && ly < Hin) {
        const float* img = (n < B_) ? (ref + ((size_t)n * 3 + ci) * Hin * Win)
                                    : (ngh + ((size_t)(n - B_) * 3 + ci) * Hin * Win);
        val = img[(size_t)ly * Win + lx];
    }
    __hip_bfloat16 h = __float2bfloat16(val);
    float hf = __bfloat162float(h);
    __hip_bfloat16 l = __float2bfloat16(val - hf);
    ihi[idx] = *reinterpret_cast<ushort*>(&h);
    ilo[idx] = *reinterpret_cast<ushort*>(&l);
}

// ---------------- zero padded-border cells of f1 and f2 ----------------
__global__ void zerob_kernel(ushort* __restrict__ f1hi, ushort* __restrict__ f1lo,
                             ushort* __restrict__ f2hi, ushort* __restrict__ f2lo) {
    const int F1B = 2 * P1W + 2 * (P1H - 2);
    const int F2B = 2 * P2W + 2 * (P2H - 2);
    const int f1tot = NIMG * F1B * C1;
    const int f2tot = NIMG * F2B * C_;
    int idx = blockIdx.x * 256 + threadIdx.x;
    if (idx < f1tot) {
        int c = idx & 31; int r = idx >> 5;
        int n = r / F1B; int bp = r % F1B;
        int y, x;
        if (bp < P1W)            { y = 0;        x = bp; }
        else if (bp < 2*P1W)     { y = P1H - 1;  x = bp - P1W; }
        else if (bp < 2*P1W + (P1H-2)) { y = bp - 2*P1W + 1;   x = 0; }
        else                     { y = bp - 2*P1W - (P1H-2) + 1; x = P1W - 1; }
        size_t o = (((size_t)n * P1H + y) * P1W + x) * C1 + c;
        f1hi[o] = 0; f1lo[o] = 0;
        return;
    }
    idx -= f1tot;
    if (idx < f2tot) {
        int c = idx & 63; int r = idx >> 6;
        int n = r / F2B; int bp = r % F2B;
        int y, x;
        if (bp < P2W)            { y = 0;        x = bp; }
        else if (bp < 2*P2W)     { y = P2H - 1;  x = bp - P2W; }
        else if (bp < 2*P2W + (P2H-2)) { y = bp - 2*P2W + 1;   x = 0; }
        else                     { y = bp - 2*P2W - (P2H-2) + 1; x = P2W - 1; }
        size_t o = (((size_t)n * P2H + y) * P2W + x) * C_ + c;
        f2hi[o] = 0; f2lo[o] = 0;
    }
}

// ---------------- geometry: A = K R Kinv, c = K t ----------------
__global__ void geom_kernel(const float* __restrict__ poses,
                            const float* __restrict__ Kmat,
                            float* __restrict__ geom) {
    int i = threadIdx.x;         // (b*V + v)
    if (i >= B_ * V_) return;
    int b = i / V_;
    const float* Kb = Kmat + b * 9;
    float k00=Kb[0],k01=Kb[1],k02=Kb[2];
    float k10=Kb[3],k11=Kb[4],k12=Kb[5];
    float k20=Kb[6],k21=Kb[7],k22=Kb[8];
    float det = k00*(k11*k22-k12*k21) - k01*(k10*k22-k12*k20) + k02*(k10*k21-k11*k20);
    float id = 1.0f / det;
    float ki[9];
    ki[0]=(k11*k22-k12*k21)*id; ki[1]=(k02*k21-k01*k22)*id; ki[2]=(k01*k12-k02*k11)*id;
    ki[3]=(k12*k20-k10*k22)*id; ki[4]=(k00*k22-k02*k20)*id; ki[5]=(k02*k10-k00*k12)*id;
    ki[6]=(k10*k21-k11*k20)*id; ki[7]=(k01*k20-k00*k21)*id; ki[8]=(k00*k11-k01*k10)*id;
    const float* P = poses + i * 16;
    float R[9] = {P[0],P[1],P[2], P[4],P[5],P[6], P[8],P[9],P[10]};
    float t[3] = {P[3],P[7],P[11]};
    float KR[9];
    for (int r = 0; r < 3; r++)
        for (int c = 0; c < 3; c++)
            KR[r*3+c] = Kb[r*3+0]*R[0*3+c] + Kb[r*3+1]*R[1*3+c] + Kb[r*3+2]*R[2*3+c];
    float* g = geom + i * 12;
    for (int r = 0; r < 3; r++)
        for (int c = 0; c < 3; c++)
            g[r*3+c] = KR[r*3+0]*ki[0*3+c] + KR[r*3+1]*ki[1*3+c] + KR[r*3+2]*ki[2*3+c];
    for (int r = 0; r < 3; r++)
        g[9+r] = Kb[r*3+0]*t[0] + Kb[r*3+1]*t[1] + Kb[r*3+2]*t[2];
}

// ---------------- conv1 MFMA: 3->32, 7x7, s2, p3, ReLU. P=2 px-tiles ----------
// wave: 32 px x 32 co; block 4 waves = 128 px; grid (600, NIMG)
__global__ __launch_bounds__(256) void conv1_mfma(
        const ushort* __restrict__ ihi, const ushort* __restrict__ ilo,
        const ushort* __restrict__ w1p, const float* __restrict__ b1,
        ushort* __restrict__ f1hi, ushort* __restrict__ f1lo) {
    const int lane = threadIdx.x & 63;
    const int wv   = threadIdx.x >> 6;
    const int n    = blockIdx.y;
    const int bx   = swz8(blockIdx.x, 600);
    const int px0  = bx * 128 + wv * 32;
    const int p0   = px0 + (lane & 15);
    const int p1   = p0 + 16;
    const int y0 = p0 / W2, x0 = p0 % W2;
    const int y1 = p1 / W2, x1 = p1 % W2;
    const int kg = lane >> 4;
    const ushort* ih = ihi + (size_t)n * 3 * PIH * PIW;
    const ushort* il = ilo + (size_t)n * 3 * PIH * PIW;

    f32x4 acc[2][2] = {};
#pragma unroll
    for (int s = 0; s < 6; s++) {
        const int g = s * 4 + kg;
        short8 a0h = {}, a0l = {}, a1h = {}, a1l = {};
        if (g < 21) {
            const int ci = g / 7, ky = g % 7;
            const size_t o0 = ((size_t)(ci * PIH + 2 * y0 + ky)) * PIW + 2 * x0;
            const size_t o1 = ((size_t)(ci * PIH + 2 * y1 + ky)) * PIW + 2 * x1;
            a0h = *reinterpret_cast<const short8*>(ih + o0);
            a0l = *reinterpret_cast<const short8*>(il + o0);
            a1h = *reinterpret_cast<const short8*>(ih + o1);
            a1l = *reinterpret_cast<const short8*>(il + o1);
        }
#pragma unroll
        for (int t = 0; t < 2; t++) {
            const int widx = ((t * 6 + s) * 64 + lane) * 8;
            short8 bhi = *reinterpret_cast<const short8*>(w1p + widx);
            short8 blo = *reinterpret_cast<const short8*>(w1p + 6144 + widx);
            acc[t][0] = __builtin_amdgcn_mfma_f32_16x16x32_bf16(a0h, bhi, acc[t][0], 0, 0, 0);
            acc[t][0] = __builtin_amdgcn_mfma_f32_16x16x32_bf16(a0h, blo, acc[t][0], 0, 0, 0);
            acc[t][0] = __builtin_amdgcn_mfma_f32_16x16x32_bf16(a0l, bhi, acc[t][0], 0, 0, 0);
            acc[t][1] = __builtin_amdgcn_mfma_f32_16x16x32_bf16(a1h, bhi, acc[t][1], 0, 0, 0);
            acc[t][1] = __builtin_amdgcn_mfma_f32_16x16x32_bf16(a1h, blo, acc[t][1], 0, 0, 0);
            acc[t][1] = __builtin_amdgcn_mfma_f32_16x16x32_bf16(a1l, bhi, acc[t][1], 0, 0, 0);
        }
    }
#pragma unroll
    for (int t = 0; t < 2; t++) {
        const int co = t * 16 + (lane & 15);
        const float bias = b1[co];
#pragma unroll
        for (int pt = 0; pt < 2; pt++) {
#pragma unroll
            for (int j = 0; j < 4; j++) {
                const int pr = px0 + pt * 16 + kg * 4 + j;
                const int oy = pr / W2, ox = pr % W2;
                float val = fmaxf(acc[t][pt][j] + bias, 0.0f);
                __hip_bfloat16 h = __float2bfloat16(val);
                float hf = __bfloat162float(h);
                __hip_bfloat16 l = __float2bfloat16(val - hf);
                const size_t o = (((size_t)n * P1H + (oy + 1)) * P1W + (ox + 1)) * C1 + co;
                f1hi[o] = *reinterpret_cast<ushort*>(&h);
                f1lo[o] = *reinterpret_cast<ushort*>(&l);
            }
        }
    }
}

// ---------------- conv2 MFMA: 32->64, 3x3, s2, p1, ReLU. P=2 px-tiles --------
// wave: 32 px x 64 co; grid (150, NIMG)
__global__ __launch_bounds__(256) void conv2_mfma(
        const ushort* __restrict__ f1hi, const ushort* __restrict__ f1lo,
        const ushort* __restrict__ w2p, const float* __restrict__ b2,
        ushort* __restrict__ f2hi, ushort* __restrict__ f2lo) {
    const int lane = threadIdx.x & 63;
    const int wv   = threadIdx.x >> 6;
    const int n    = blockIdx.y;
    const int bx   = swz8(blockIdx.x, 150);
    const int px0  = bx * 128 + wv * 32;
    const int p0   = px0 + (lane & 15);
    const int p1   = p0 + 16;
    const int y0 = p0 / W4, x0 = p0 % W4;
    const int y1 = p1 / W4, x1 = p1 % W4;
    const int kg = lane >> 4;                 // 0..3
    const ushort* ihi = f1hi + (size_t)n * P1H * P1W * C1;
    const ushort* ilo = f1lo + (size_t)n * P1H * P1W * C1;

    f32x4 acc[4][2] = {};
#pragma unroll
    for (int s = 0; s < 9; s++) {
        const int ky = s / 3, kx = s % 3;
        const int o0 = ((2 * y0 + ky) * P1W + (2 * x0 + kx)) * C1 + kg * 8;
        const int o1 = ((2 * y1 + ky) * P1W + (2 * x1 + kx)) * C1 + kg * 8;
        short8 a0h = *reinterpret_cast<const short8*>(ihi + o0);
        short8 a0l = *reinterpret_cast<const short8*>(ilo + o0);
        short8 a1h = *reinterpret_cast<const short8*>(ihi + o1);
        short8 a1l = *reinterpret_cast<const short8*>(ilo + o1);
#pragma unroll
        for (int t = 0; t < 4; t++) {
            const int widx = ((t * 9 + s) * 64 + lane) * 8;
            short8 bhi = *reinterpret_cast<const short8*>(w2p + widx);
            short8 blo = *reinterpret_cast<const short8*>(w2p + 18432 + widx);
            acc[t][0] = __builtin_amdgcn_mfma_f32_16x16x32_bf16(a0h, bhi, acc[t][0], 0, 0, 0);
            acc[t][0] = __builtin_amdgcn_mfma_f32_16x16x32_bf16(a0h, blo, acc[t][0], 0, 0, 0);
            acc[t][0] = __builtin_amdgcn_mfma_f32_16x16x32_bf16(a0l, bhi, acc[t][0], 0, 0, 0);
            acc[t][1] = __builtin_amdgcn_mfma_f32_16x16x32_bf16(a1h, bhi, acc[t][1], 0, 0, 0);
            acc[t][1] = __builtin_amdgcn_mfma_f32_16x16x32_bf16(a1h, blo, acc[t][1], 0, 0, 0);
            acc[t][1] = __builtin_amdgcn_mfma_f32_16x16x32_bf16(a1l, bhi, acc[t][1], 0, 0, 0);
        }
    }
    ushort* ohi = f2hi + (size_t)n * P2H * P2W * C_;
    ushort* olo = f2lo + (size_t)n * P2H * P2W * C_;
#pragma unroll
    for (int t = 0; t < 4; t++) {
        const int co = t * 16 + (lane & 15);
        const float bias = b2[co];
#pragma unroll
        for (int pt = 0; pt < 2; pt++) {
#pragma unroll
            for (int j = 0; j < 4; j++) {
                const int pr = px0 + pt * 16 + kg * 4 + j;
                const int yy = pr / W4, xx = pr % W4;
                float val = fmaxf(acc[t][pt][j] + bias, 0.0f);
                __hip_bfloat16 h = __float2bfloat16(val);
                float hf = __bfloat162float(h);
                __hip_bfloat16 l = __float2bfloat16(val - hf);
                const size_t o = (((size_t)(yy + 1)) * P2W + (xx + 1)) * C_ + co;
                ohi[o] = *reinterpret_cast<ushort*>(&h);
                olo[o] = *reinterpret_cast<ushort*>(&l);
            }
        }
    }
}

// ---------------- conv3 MFMA: 64->64, 3x3, s1, p1. P=2 px-tiles. out fp32 ----
// wave: 32 px x 64 co; grid (150, NIMG)
__global__ __launch_bounds__(256) void conv3_mfma(
        const ushort* __restrict__ f2hi, const ushort* __restrict__ f2lo,
        const ushort* __restrict__ w3p, const float* __restrict__ b3,
        float* __restrict__ f3) {
    const int lane = threadIdx.x & 63;
    const int wv   = threadIdx.x >> 6;
    const int n    = blockIdx.y;
    const int bx   = swz8(blockIdx.x, 150);
    const int px0  = bx * 128 + wv * 32;
    const int p0   = px0 + (lane & 15);
    const int p1   = p0 + 16;
    const int y0 = p0 / W4, x0 = p0 % W4;
    const int y1 = p1 / W4, x1 = p1 % W4;
    const int kg = lane >> 4;
    const ushort* ihi = f2hi + (size_t)n * P2H * P2W * C_;
    const ushort* ilo = f2lo + (size_t)n * P2H * P2W * C_;

    f32x4 acc[4][2] = {};
#pragma unroll
    for (int s = 0; s < 18; s++) {
        const int kyx = s >> 1;
        const int ky = kyx / 3, kx = kyx % 3;
        const int ci0 = (s & 1) * 32 + kg * 8;
        const int o0 = ((y0 + ky) * P2W + (x0 + kx)) * C_ + ci0;
        const int o1 = ((y1 + ky) * P2W + (x1 + kx)) * C_ + ci0;
        short8 a0h = *reinterpret_cast<const short8*>(ihi + o0);
        short8 a0l = *reinterpret_cast<const short8*>(ilo + o0);
        short8 a1h = *reinterpret_cast<const short8*>(ihi + o1);
        short8 a1l = *reinterpret_cast<const short8*>(ilo + o1);
#pragma unroll
        for (int t = 0; t < 4; t++) {
            const int widx = ((t * 18 + s) * 64 + lane) * 8;
            short8 bhi = *reinterpret_cast<const short8*>(w3p + widx);
            short8 blo = *reinterpret_cast<const short8*>(w3p + 36864 + widx);
            acc[t][0] = __builtin_amdgcn_mfma_f32_16x16x32_bf16(a0h, bhi, acc[t][0], 0, 0, 0);
            acc[t][0] = __builtin_amdgcn_mfma_f32_16x16x32_bf16(a0h, blo, acc[t][0], 0, 0, 0);
            acc[t][0] = __builtin_amdgcn_mfma_f32_16x16x32_bf16(a0l, bhi, acc[t][0], 0, 0, 0);
            acc[t][1] = __builtin_amdgcn_mfma_f32_16x16x32_bf16(a1h, bhi, acc[t][1], 0, 0, 0);
            acc[t][1] = __builtin_amdgcn_mfma_f32_16x16x32_bf16(a1h, blo, acc[t][1], 0, 0, 0);
            acc[t][1] = __builtin_amdgcn_mfma_f32_16x16x32_bf16(a1l, bhi, acc[t][1], 0, 0, 0);
        }
    }
    float* op = f3 + (size_t)n * H4 * W4 * C_;
#pragma unroll
    for (int t = 0; t < 4; t++) {
        const int co = t * 16 + (lane & 15);
        const float bias = b3[co];
#pragma unroll
        for (int pt = 0; pt < 2; pt++) {
#pragma unroll
            for (int j = 0; j < 4; j++) {
                const int pr = px0 + pt * 16 + kg * 4 + j;
                op[(size_t)pr * C_ + co] = acc[t][pt][j] + bias;
            }
        }
    }
}

// ---------------- sample geometry: one thread per (b,v,d,h,w) ----------------
// record: sw = {w00,w01,w10,w11}; sm = off00 | off10<<15 | mask<<30
__global__ void samp_kernel(const float* __restrict__ geom,
                            const float* __restrict__ dc,
                            const int*   __restrict__ valid,
                            f32x4* __restrict__ sw, int* __restrict__ sm) {
    int idx = blockIdx.x * 256 + threadIdx.x;
    if (idx >= B_ * V_ * D_ * HW4) return;
    int hw = idx % HW4;
    int r  = idx / HW4;
    int d = r % D_;  r /= D_;
    int v = r % V_;  int b = r / V_;
    int h = hw / W4, w = hw % W4;

    float dep = dc[((size_t)(b * D_ + d)) * HW4 + hw];
    const float* g = geom + (b * V_ + v) * 12;
    float px = dep * (g[0] * w + g[1] * h + g[2]) + g[9];
    float py = dep * (g[3] * w + g[4] * h + g[5]) + g[10];
    float pz = dep * (g[6] * w + g[7] * h + g[8]) + g[11];
    bool zok = pz > 0.001f;
    float zc = fmaxf(pz, 0.001f);
    float u  = px / zc;
    float vv = py / zc;
    bool inb = (u >= 0.f) && (u <= (float)(W4 - 1)) &&
               (vv >= 0.f) && (vv <= (float)(H4 - 1));
    bool m = zok && inb && (valid[b * V_ + v] != 0);

    f32x4 wgt = {0.f, 0.f, 0.f, 0.f};
    int rec = 0;
    if (m) {
        float u0f = floorf(u), v0f = floorf(vv);
        float du = u - u0f, dv = vv - v0f;
        int u0 = (int)u0f, v0 = (int)v0f;
        int off00 = v0 * W4 + u0;
        int off10 = min(v0 + 1, H4 - 1) * W4 + u0;
        wgt[0] = (1.f - du) * (1.f - dv);
        wgt[1] = du * (1.f - dv);
        wgt[2] = (1.f - du) * dv;
        wgt[3] = du * dv;
        rec = off00 | (off10 << 15) | (1 << 30);
    }
    sw[idx] = wgt;
    sm[idx] = rec;
}

// ---------------- warp + cost volume. one wave per (b,h,w) ----------------
__global__ __launch_bounds__(256) void warpcost_kernel(
        const float* __restrict__ feat,   // NHWC, 10 imgs
        const f32x4* __restrict__ sw, const int* __restrict__ sm,
        float* __restrict__ out) {
    const int wave = threadIdx.x >> 6;
    const int lane = threadIdx.x & 63;
    int pid = blockIdx.x * 4 + wave;  // 0 .. B*HW4-1
    int b = pid / HW4;
    int hw = pid % HW4;

    const float refc = feat[((size_t)b * HW4 + hw) * C_ + lane];

    float accv[D_] = {0.f, 0.f, 0.f, 0.f, 0.f};
    float den[D_]  = {0.f, 0.f, 0.f, 0.f, 0.f};

#pragma unroll
    for (int v = 0; v < V_; v++) {
        const float* fimg = feat + (size_t)(B_ + b * V_ + v) * HW4 * C_;
        const int rbase = ((b * V_ + v) * D_) * HW4 + hw;
#pragma unroll
        for (int d = 0; d < D_; d++) {
            int rec  = sm[rbase + d * HW4];
            f32x4 wv = sw[rbase + d * HW4];
            int off00 = rec & 0x7FFF;
            int off10 = (rec >> 15) & 0x7FFF;
            const float* p0 = fimg + (size_t)off00 * C_ + lane;
            const float* p1 = fimg + (size_t)off10 * C_ + lane;
            accv[d] += p0[0] * wv[0] + p0[C_] * wv[1] + p1[0] * wv[2] + p1[C_] * wv[3];
            den[d]  += (float)((rec >> 30) & 1);
        }
    }

#pragma unroll
    for (int d = 0; d < D_; d++) {
        float s = refc * accv[d];
        for (int off = 32; off > 0; off >>= 1) s += __shfl_xor(s, off, 64);
        if (lane == 0) {
            out[((size_t)b * D_ + d) * HW4 + hw] =
                (s * (1.0f / (float)C_)) / fmaxf(den[d], 1.0f);
        }
    }
}

extern "C" void kernel_launch(void* const* d_in, const int* in_sizes, int n_in,
                              void* d_out, int out_size, void* d_ws, size_t ws_size,
                              hipStream_t stream) {
    const float* ref_img  = (const float*)d_in[0];
    const float* ngh_img  = (const float*)d_in[1];
    const float* poses    = (const float*)d_in[2];
    const int*   is_valid = (const int*)  d_in[3];
    const float* K        = (const float*)d_in[4];
    const float* dc       = (const float*)d_in[5];
    const float* w1 = (const float*)d_in[6];
    const float* b1 = (const float*)d_in[7];
    const float* w2 = (const float*)d_in[8];
    const float* b2 = (const float*)d_in[9];
    const float* w3 = (const float*)d_in[10];
    const float* b3 = (const float*)d_in[11];
    float* out = (float*)d_out;

    float* ws = (float*)d_ws;
    ushort* f1hi = (ushort*)(ws + OFF_F1HI);
    ushort* f1lo = (ushort*)(ws + OFF_F1LO);
    ushort* f2hi = (ushort*)(ws + OFF_F2HI);
    ushort* f2lo = (ushort*)(ws + OFF_F2LO);
    ushort* inhi = (ushort*)(ws + OFF_INHI);  // aliases f2 region (dead after conv1)
    ushort* inlo = (ushort*)(ws + OFF_INLO);
    float*  f3   = ws + OFF_F3;               // overlaps f1hi (dead after conv2)
    f32x4*  sw   = (f32x4*)(ws + OFF_SAMPW);  // aliases f1lo (dead after conv2)
    int*    sm   = (int*)  (ws + OFF_SAMPM);
    float*  geom = ws + OFF_GEOM;
    ushort* w1p  = (ushort*)(ws + OFF_W1P);
    ushort* w2p  = (ushort*)(ws + OFF_W2P);
    ushort* w3p  = (ushort*)(ws + OFF_W3P);

    geom_kernel<<<1, 64, 0, stream>>>(poses, K, geom);
    packw1_kernel<<<24, 256, 0, stream>>>(w1, w1p);
    packw_kernel<<<(4*9*64*8 + 255)/256, 256, 0, stream>>>(w2, w2p, C1, 9, 18432);
    packw_kernel<<<(4*18*64*8 + 255)/256, 256, 0, stream>>>(w3, w3p, C_, 18, 36864);
    packin_kernel<<<(NIMG*3*PIH*PIW + 255)/256, 256, 0, stream>>>(ref_img, ngh_img, inhi, inlo);

    conv1_mfma<<<dim3(H2*W2/128, NIMG), 256, 0, stream>>>(inhi, inlo, w1p, b1, f1hi, f1lo);
    {
        const int ztot = NIMG*(2*P1W + 2*(P1H-2))*C1 + NIMG*(2*P2W + 2*(P2H-2))*C_;
        zerob_kernel<<<(ztot + 255)/256, 256, 0, stream>>>(f1hi, f1lo, f2hi, f2lo);
    }
    conv2_mfma<<<dim3(H4*W4/128, NIMG), 256, 0, stream>>>(f1hi, f1lo, w2p, b2, f2hi, f2lo);
    // samp writes into the f1lo alias -> must follow conv2 (stream-ordered)
    samp_kernel<<<(B_*V_*D_*HW4 + 255)/256, 256, 0, stream>>>(geom, dc, is_valid, sw, sm);
    conv3_mfma<<<dim3(H4*W4/128, NIMG), 256, 0, stream>>>(f2hi, f2lo, w3p, b3, f3);

    warpcost_kernel<<<(B_*HW4)/4, 256, 0, stream>>>(f3, sw, sm, out);
}

// Round 11
// 380.749 us; speedup vs baseline: 1.9189x; 1.0703x over previous
//
#include <hip/hip_runtime.h>
#include <hip/hip_bf16.h>

// Problem constants
#define B_  2
#define V_  4
#define Hin 480
#define Win 640
#define H2  240   // after conv1 (s2)
#define W2  320
#define H4  120   // after conv2 (s2)
#define W4  160
#define C1  32
#define C_  64
#define D_  5
#define NIMG 10  // B + B*V
#define HW4 (H4*W4)

// padded feature dims
#define P1H 242
#define P1W 322
#define P2H 122
#define P2W 162
// padded raw-input dims (for conv1 MFMA)
#define PIH 486
#define PIW 646

typedef __attribute__((ext_vector_type(8))) short short8;
typedef __attribute__((ext_vector_type(4))) float f32x4;

// ---------------- workspace layout (float offsets) ----------------
#define OFF_F1HI 0
#define OFF_F1LO 12467840
#define OFF_F2HI 24935680
#define OFF_F2LO 31260160
#define OFF_INHI 24935680
#define OFF_INLO 29645504
#define OFF_F3   0
#define OFF_SAMPW 12467840
#define OFF_SAMPM 15539840
#define OFF_GEOM 37584640
#define OFF_W1P  37584736   // ushort[2*6144]: hi then lo
#define OFF_W2P  37590880   // ushort[2*18432]: hi then lo
#define OFF_W3P  37609312   // ushort[2*36864]: hi then lo

// bijective XCD-aware block swizzle (m204): consecutive output tiles -> same XCD
__device__ __forceinline__ int swz8(int o, int n) {
    int x = o & 7, i = o >> 3, q = n >> 3, r = n & 7;
    return (x < r) ? (x * (q + 1) + i) : (r * (q + 1) + (x - r) * q + i);
}

// ---------------- pack conv2/conv3 weights into MFMA B-fragment order ----
__global__ void packw_kernel(const float* __restrict__ w, ushort* __restrict__ dst,
                             int CI, int NK, int lo_off) {
    int idx = blockIdx.x * 256 + threadIdx.x;
    int total = 4 * NK * 64 * 8;
    if (idx >= total) return;
    int j = idx & 7;
    int lane = (idx >> 3) & 63;
    int s = (idx >> 9) % NK;
    int t = idx / (NK * 512);
    int k = s * 32 + (lane >> 4) * 8 + j;
    int co = t * 16 + (lane & 15);
    int kyx = k / CI;
    int ci  = k % CI;
    int ky = kyx / 3, kx = kyx % 3;
    float val = w[((co * CI + ci) * 3 + ky) * 3 + kx];
    __hip_bfloat16 h = __float2bfloat16(val);
    float hf = __bfloat162float(h);
    __hip_bfloat16 l = __float2bfloat16(val - hf);
    dst[idx]          = *reinterpret_cast<ushort*>(&h);
    dst[lo_off + idx] = *reinterpret_cast<ushort*>(&l);
}

// ---------------- pack conv1 weights ----
__global__ void packw1_kernel(const float* __restrict__ w, ushort* __restrict__ dst) {
    int idx = blockIdx.x * 256 + threadIdx.x;
    if (idx >= 6144) return;
    int j = idx & 7;
    int lane = (idx >> 3) & 63;
    int s = (idx >> 9) % 6;
    int t = idx / 3072;
    int g = s * 4 + (lane >> 4);
    int co = t * 16 + (lane & 15);
    float val = 0.0f;
    if (g < 21 && j < 7) {
        int ci = g / 7, ky = g % 7;
        val = w[((co * 3 + ci) * 7 + ky) * 7 + j];
    }
    __hip_bfloat16 h = __float2bfloat16(val);
    float hf = __bfloat162float(h);
    __hip_bfloat16 l = __float2bfloat16(val - hf);
    dst[idx]        = *reinterpret_cast<ushort*>(&h);
    dst[6144 + idx] = *reinterpret_cast<ushort*>(&l);
}

// ---------------- pack raw images to padded NCHW bf16 hi/lo ----------------
__global__ void packin_kernel(const float* __restrict__ ref, const float* __restrict__ ngh,
                              ushort* __restrict__ ihi, ushort* __restrict__ ilo) {
    int idx = blockIdx.x * 256 + threadIdx.x;
    const int tot = NIMG * 3 * PIH * PIW;
    if (idx >= tot) return;
    int x = idx % PIW;
    int r = idx / PIW;
    int y = r % PIH;
    int rc = r / PIH;
    int ci = rc % 3;
    int n  = rc / 3;
    float val = 0.0f;
    int lx = x - 3, ly = y - 3;
    if (lx >= 0 && lx < Win && ly >= 0 && ly < Hin) {
        const float* img = (n < B_) ? (ref + ((size_t)n * 3 + ci) * Hin * Win)
                                    : (ngh + ((size_t)(n - B_) * 3 + ci) * Hin * Win);
        val = img[(size_t)ly * Win + lx];
    }
    __hip_bfloat16 h = __float2bfloat16(val);
    float hf = __bfloat162float(h);
    __hip_bfloat16 l = __float2bfloat16(val - hf);
    ihi[idx] = *reinterpret_cast<ushort*>(&h);
    ilo[idx] = *reinterpret_cast<ushort*>(&l);
}

// ---------------- zero padded-border cells of f1 and f2 ----------------
__global__ void zerob_kernel(ushort* __restrict__ f1hi, ushort* __restrict__ f1lo,
                             ushort* __restrict__ f2hi, ushort* __restrict__ f2lo) {
    const int F1B = 2 * P1W + 2 * (P1H - 2);
    const int F2B = 2 * P2W + 2 * (P2H - 2);
    const int f1tot = NIMG * F1B * C1;
    const int f2tot = NIMG * F2B * C_;
    int idx = blockIdx.x * 256 + threadIdx.x;
    if (idx < f1tot) {
        int c = idx & 31; int r = idx >> 5;
        int n = r / F1B; int bp = r % F1B;
        int y, x;
        if (bp < P1W)            { y = 0;        x = bp; }
        else if (bp < 2*P1W)     { y = P1H - 1;  x = bp - P1W; }
        else if (bp < 2*P1W + (P1H-2)) { y = bp - 2*P1W + 1;   x = 0; }
        else                     { y = bp - 2*P1W - (P1H-2) + 1; x = P1W - 1; }
        size_t o = (((size_t)n * P1H + y) * P1W + x) * C1 + c;
        f1hi[o] = 0; f1lo[o] = 0;
        return;
    }
    idx -= f1tot;
    if (idx < f2tot) {
        int c = idx & 63; int r = idx >> 6;
        int n = r / F2B; int bp = r % F2B;
        int y, x;
        if (bp < P2W)            { y = 0;        x = bp; }
        else if (bp < 2*P2W)     { y = P2H - 1;  x = bp - P2W; }
        else if (bp < 2*P2W + (P2H-2)) { y = bp - 2*P2W + 1;   x = 0; }
        else                     { y = bp - 2*P2W - (P2H-2) + 1; x = P2W - 1; }
        size_t o = (((size_t)n * P2H + y) * P2W + x) * C_ + c;
        f2hi[o] = 0; f2lo[o] = 0;
    }
}

// ---------------- geometry: A = K R Kinv, c = K t ----------------
__global__ void geom_kernel(const float* __restrict__ poses,
                            const float* __restrict__ Kmat,
                            float* __restrict__ geom) {
    int i = threadIdx.x;         // (b*V + v)
    if (i >= B_ * V_) return;
    int b = i / V_;
    const float* Kb = Kmat + b * 9;
    float k00=Kb[0],k01=Kb[1],k02=Kb[2];
    float k10=Kb[3],k11=Kb[4],k12=Kb[5];
    float k20=Kb[6],k21=Kb[7],k22=Kb[8];
    float det = k00*(k11*k22-k12*k21) - k01*(k10*k22-k12*k20) + k02*(k10*k21-k11*k20);
    float id = 1.0f / det;
    float ki[9];
    ki[0]=(k11*k22-k12*k21)*id; ki[1]=(k02*k21-k01*k22)*id; ki[2]=(k01*k12-k02*k11)*id;
    ki[3]=(k12*k20-k10*k22)*id; ki[4]=(k00*k22-k02*k20)*id; ki[5]=(k02*k10-k00*k12)*id;
    ki[6]=(k10*k21-k11*k20)*id; ki[7]=(k01*k20-k00*k21)*id; ki[8]=(k00*k11-k01*k10)*id;
    const float* P = poses + i * 16;
    float R[9] = {P[0],P[1],P[2], P[4],P[5],P[6], P[8],P[9],P[10]};
    float t[3] = {P[3],P[7],P[11]};
    float KR[9];
    for (int r = 0; r < 3; r++)
        for (int c = 0; c < 3; c++)
            KR[r*3+c] = Kb[r*3+0]*R[0*3+c] + Kb[r*3+1]*R[1*3+c] + Kb[r*3+2]*R[2*3+c];
    float* g = geom + i * 12;
    for (int r = 0; r < 3; r++)
        for (int c = 0; c < 3; c++)
            g[r*3+c] = KR[r*3+0]*ki[0*3+c] + KR[r*3+1]*ki[1*3+c] + KR[r*3+2]*ki[2*3+c];
    for (int r = 0; r < 3; r++)
        g[9+r] = Kb[r*3+0]*t[0] + Kb[r*3+1]*t[1] + Kb[r*3+2]*t[2];
}

// ---------------- conv1 MFMA: 3->32, 7x7, s2, p3, ReLU. P=2 px-tiles ----------
// wave: 32 px x 32 co; block 4 waves = 128 px; grid (600, NIMG)
__global__ __launch_bounds__(256) void conv1_mfma(
        const ushort* __restrict__ ihi, const ushort* __restrict__ ilo,
        const ushort* __restrict__ w1p, const float* __restrict__ b1,
        ushort* __restrict__ f1hi, ushort* __restrict__ f1lo) {
    const int lane = threadIdx.x & 63;
    const int wv   = threadIdx.x >> 6;
    const int n    = blockIdx.y;
    const int bx   = swz8(blockIdx.x, 600);
    const int px0  = bx * 128 + wv * 32;
    const int p0   = px0 + (lane & 15);
    const int p1   = p0 + 16;
    const int y0 = p0 / W2, x0 = p0 % W2;
    const int y1 = p1 / W2, x1 = p1 % W2;
    const int kg = lane >> 4;
    const ushort* ih = ihi + (size_t)n * 3 * PIH * PIW;
    const ushort* il = ilo + (size_t)n * 3 * PIH * PIW;

    f32x4 acc[2][2] = {};
#pragma unroll
    for (int s = 0; s < 6; s++) {
        const int g = s * 4 + kg;
        short8 a0h = {}, a0l = {}, a1h = {}, a1l = {};
        if (g < 21) {
            const int ci = g / 7, ky = g % 7;
            const size_t o0 = ((size_t)(ci * PIH + 2 * y0 + ky)) * PIW + 2 * x0;
            const size_t o1 = ((size_t)(ci * PIH + 2 * y1 + ky)) * PIW + 2 * x1;
            a0h = *reinterpret_cast<const short8*>(ih + o0);
            a0l = *reinterpret_cast<const short8*>(il + o0);
            a1h = *reinterpret_cast<const short8*>(ih + o1);
            a1l = *reinterpret_cast<const short8*>(il + o1);
        }
#pragma unroll
        for (int t = 0; t < 2; t++) {
            const int widx = ((t * 6 + s) * 64 + lane) * 8;
            short8 bhi = *reinterpret_cast<const short8*>(w1p + widx);
            short8 blo = *reinterpret_cast<const short8*>(w1p + 6144 + widx);
            acc[t][0] = __builtin_amdgcn_mfma_f32_16x16x32_bf16(a0h, bhi, acc[t][0], 0, 0, 0);
            acc[t][0] = __builtin_amdgcn_mfma_f32_16x16x32_bf16(a0h, blo, acc[t][0], 0, 0, 0);
            acc[t][0] = __builtin_amdgcn_mfma_f32_16x16x32_bf16(a0l, bhi, acc[t][0], 0, 0, 0);
            acc[t][1] = __builtin_amdgcn_mfma_f32_16x16x32_bf16(a1h, bhi, acc[t][1], 0, 0, 0);
            acc[t][1] = __builtin_amdgcn_mfma_f32_16x16x32_bf16(a1h, blo, acc[t][1], 0, 0, 0);
            acc[t][1] = __builtin_amdgcn_mfma_f32_16x16x32_bf16(a1l, bhi, acc[t][1], 0, 0, 0);
        }
    }
#pragma unroll
    for (int t = 0; t < 2; t++) {
        const int co = t * 16 + (lane & 15);
        const float bias = b1[co];
#pragma unroll
        for (int pt = 0; pt < 2; pt++) {
#pragma unroll
            for (int j = 0; j < 4; j++) {
                const int pr = px0 + pt * 16 + kg * 4 + j;
                const int oy = pr / W2, ox = pr % W2;
                float val = fmaxf(acc[t][pt][j] + bias, 0.0f);
                __hip_bfloat16 h = __float2bfloat16(val);
                float hf = __bfloat162float(h);
                __hip_bfloat16 l = __float2bfloat16(val - hf);
                const size_t o = (((size_t)n * P1H + (oy + 1)) * P1W + (ox + 1)) * C1 + co;
                f1hi[o] = *reinterpret_cast<ushort*>(&h);
                f1lo[o] = *reinterpret_cast<ushort*>(&l);
            }
        }
    }
}

// ---------------- conv2 MFMA: 32->64, 3x3, s2, p1, ReLU. P=2 px-tiles --------
// wave: 32 px x 64 co; grid (150, NIMG)
__global__ __launch_bounds__(256) void conv2_mfma(
        const ushort* __restrict__ f1hi, const ushort* __restrict__ f1lo,
        const ushort* __restrict__ w2p, const float* __restrict__ b2,
        ushort* __restrict__ f2hi, ushort* __restrict__ f2lo) {
    const int lane = threadIdx.x & 63;
    const int wv   = threadIdx.x >> 6;
    const int n    = blockIdx.y;
    const int bx   = swz8(blockIdx.x, 150);
    const int px0  = bx * 128 + wv * 32;
    const int p0   = px0 + (lane & 15);
    const int p1   = p0 + 16;
    const int y0 = p0 / W4, x0 = p0 % W4;
    const int y1 = p1 / W4, x1 = p1 % W4;
    const int kg = lane >> 4;                 // 0..3
    const ushort* ihi = f1hi + (size_t)n * P1H * P1W * C1;
    const ushort* ilo = f1lo + (size_t)n * P1H * P1W * C1;

    f32x4 acc[4][2] = {};
#pragma unroll
    for (int s = 0; s < 9; s++) {
        const int ky = s / 3, kx = s % 3;
        const int o0 = ((2 * y0 + ky) * P1W + (2 * x0 + kx)) * C1 + kg * 8;
        const int o1 = ((2 * y1 + ky) * P1W + (2 * x1 + kx)) * C1 + kg * 8;
        short8 a0h = *reinterpret_cast<const short8*>(ihi + o0);
        short8 a0l = *reinterpret_cast<const short8*>(ilo + o0);
        short8 a1h = *reinterpret_cast<const short8*>(ihi + o1);
        short8 a1l = *reinterpret_cast<const short8*>(ilo + o1);
#pragma unroll
        for (int t = 0; t < 4; t++) {
            const int widx = ((t * 9 + s) * 64 + lane) * 8;
            short8 bhi = *reinterpret_cast<const short8*>(w2p + widx);
            short8 blo = *reinterpret_cast<const short8*>(w2p + 18432 + widx);
            acc[t][0] = __builtin_amdgcn_mfma_f32_16x16x32_bf16(a0h, bhi, acc[t][0], 0, 0, 0);
            acc[t][0] = __builtin_amdgcn_mfma_f32_16x16x32_bf16(a0h, blo, acc[t][0], 0, 0, 0);
            acc[t][0] = __builtin_amdgcn_mfma_f32_16x16x32_bf16(a0l, bhi, acc[t][0], 0, 0, 0);
            acc[t][1] = __builtin_amdgcn_mfma_f32_16x16x32_bf16(a1h, bhi, acc[t][1], 0, 0, 0);
            acc[t][1] = __builtin_amdgcn_mfma_f32_16x16x32_bf16(a1h, blo, acc[t][1], 0, 0, 0);
            acc[t][1] = __builtin_amdgcn_mfma_f32_16x16x32_bf16(a1l, bhi, acc[t][1], 0, 0, 0);
        }
    }
    ushort* ohi = f2hi + (size_t)n * P2H * P2W * C_;
    ushort* olo = f2lo + (size_t)n * P2H * P2W * C_;
#pragma unroll
    for (int t = 0; t < 4; t++) {
        const int co = t * 16 + (lane & 15);
        const float bias = b2[co];
#pragma unroll
        for (int pt = 0; pt < 2; pt++) {
#pragma unroll
            for (int j = 0; j < 4; j++) {
                const int pr = px0 + pt * 16 + kg * 4 + j;
                const int yy = pr / W4, xx = pr % W4;
                float val = fmaxf(acc[t][pt][j] + bias, 0.0f);
                __hip_bfloat16 h = __float2bfloat16(val);
                float hf = __bfloat162float(h);
                __hip_bfloat16 l = __float2bfloat16(val - hf);
                const size_t o = (((size_t)(yy + 1)) * P2W + (xx + 1)) * C_ + co;
                ohi[o] = *reinterpret_cast<ushort*>(&h);
                olo[o] = *reinterpret_cast<ushort*>(&l);
            }
        }
    }
}

// ---------------- conv3 MFMA: 64->64, 3x3, s1, p1. P=2 px-tiles. out fp32 ----
// wave: 32 px x 64 co; grid (150, NIMG)
__global__ __launch_bounds__(256) void conv3_mfma(
        const ushort* __restrict__ f2hi, const ushort* __restrict__ f2lo,
        const ushort* __restrict__ w3p, const float* __restrict__ b3,
        float* __restrict__ f3) {
    const int lane = threadIdx.x & 63;
    const int wv   = threadIdx.x >> 6;
    const int n    = blockIdx.y;
    const int bx   = swz8(blockIdx.x, 150);
    const int px0  = bx * 128 + wv * 32;
    const int p0   = px0 + (lane & 15);
    const int p1   = p0 + 16;
    const int y0 = p0 / W4, x0 = p0 % W4;
    const int y1 = p1 / W4, x1 = p1 % W4;
    const int kg = lane >> 4;
    const ushort* ihi = f2hi + (size_t)n * P2H * P2W * C_;
    const ushort* ilo = f2lo + (size_t)n * P2H * P2W * C_;

    f32x4 acc[4][2] = {};
#pragma unroll
    for (int s = 0; s < 18; s++) {
        const int kyx = s >> 1;
        const int ky = kyx / 3, kx = kyx % 3;
        const int ci0 = (s & 1) * 32 + kg * 8;
        const int o0 = ((y0 + ky) * P2W + (x0 + kx)) * C_ + ci0;
        const int o1 = ((y1 + ky) * P2W + (x1 + kx)) * C_ + ci0;
        short8 a0h = *reinterpret_cast<const short8*>(ihi + o0);
        short8 a0l = *reinterpret_cast<const short8*>(ilo + o0);
        short8 a1h = *reinterpret_cast<const short8*>(ihi + o1);
        short8 a1l = *reinterpret_cast<const short8*>(ilo + o1);
#pragma unroll
        for (int t = 0; t < 4; t++) {
            const int widx = ((t * 18 + s) * 64 + lane) * 8;
            short8 bhi = *reinterpret_cast<const short8*>(w3p + widx);
            short8 blo = *reinterpret_cast<const short8*>(w3p + 36864 + widx);
            acc[t][0] = __builtin_amdgcn_mfma_f32_16x16x32_bf16(a0h, bhi, acc[t][0], 0, 0, 0);
            acc[t][0] = __builtin_amdgcn_mfma_f32_16x16x32_bf16(a0h, blo, acc[t][0], 0, 0, 0);
            acc[t][0] = __builtin_amdgcn_mfma_f32_16x16x32_bf16(a0l, bhi, acc[t][0], 0, 0, 0);
            acc[t][1] = __builtin_amdgcn_mfma_f32_16x16x32_bf16(a1h, bhi, acc[t][1], 0, 0, 0);
            acc[t][1] = __builtin_amdgcn_mfma_f32_16x16x32_bf16(a1h, blo, acc[t][1], 0, 0, 0);
            acc[t][1] = __builtin_amdgcn_mfma_f32_16x16x32_bf16(a1l, bhi, acc[t][1], 0, 0, 0);
        }
    }
    float* op = f3 + (size_t)n * H4 * W4 * C_;
#pragma unroll
    for (int t = 0; t < 4; t++) {
        const int co = t * 16 + (lane & 15);
        const float bias = b3[co];
#pragma unroll
        for (int pt = 0; pt < 2; pt++) {
#pragma unroll
            for (int j = 0; j < 4; j++) {
                const int pr = px0 + pt * 16 + kg * 4 + j;
                op[(size_t)pr * C_ + co] = acc[t][pt][j] + bias;
            }
        }
    }
}

// ---------------- sample geometry: one thread per (b,v,d,h,w) ----------------
// record: sw = {w00,w01,w10,w11}; sm = off00 | off10<<15 | mask<<30
__global__ void samp_kernel(const float* __restrict__ geom,
                            const float* __restrict__ dc,
                            const int*   __restrict__ valid,
                            f32x4* __restrict__ sw, int* __restrict__ sm) {
    int idx = blockIdx.x * 256 + threadIdx.x;
    if (idx >= B_ * V_ * D_ * HW4) return;
    int hw = idx % HW4;
    int r  = idx / HW4;
    int d = r % D_;  r /= D_;
    int v = r % V_;  int b = r / V_;
    int h = hw / W4, w = hw % W4;

    float dep = dc[((size_t)(b * D_ + d)) * HW4 + hw];
    const float* g = geom + (b * V_ + v) * 12;
    float px = dep * (g[0] * w + g[1] * h + g[2]) + g[9];
    float py = dep * (g[3] * w + g[4] * h + g[5]) + g[10];
    float pz = dep * (g[6] * w + g[7] * h + g[8]) + g[11];
    bool zok = pz > 0.001f;
    float zc = fmaxf(pz, 0.001f);
    float u  = px / zc;
    float vv = py / zc;
    bool inb = (u >= 0.f) && (u <= (float)(W4 - 1)) &&
               (vv >= 0.f) && (vv <= (float)(H4 - 1));
    bool m = zok && inb && (valid[b * V_ + v] != 0);

    f32x4 wgt = {0.f, 0.f, 0.f, 0.f};
    int rec = 0;
    if (m) {
        float u0f = floorf(u), v0f = floorf(vv);
        float du = u - u0f, dv = vv - v0f;
        int u0 = (int)u0f, v0 = (int)v0f;
        int off00 = v0 * W4 + u0;
        int off10 = min(v0 + 1, H4 - 1) * W4 + u0;
        wgt[0] = (1.f - du) * (1.f - dv);
        wgt[1] = du * (1.f - dv);
        wgt[2] = (1.f - du) * dv;
        wgt[3] = du * dv;
        rec = off00 | (off10 << 15) | (1 << 30);
    }
    sw[idx] = wgt;
    sm[idx] = rec;
}

// ---------------- warp + cost volume. 4 px per wave, float4 per lane ---------
// lane = g*16 + l : g = pixel-in-group (0..3), l = channel-quad (0..15)
__global__ __launch_bounds__(256) void warpcost_kernel(
        const float* __restrict__ feat,   // NHWC fp32, 10 imgs
        const f32x4* __restrict__ sw, const int* __restrict__ sm,
        float* __restrict__ out) {
    const int wave = threadIdx.x >> 6;
    const int lane = threadIdx.x & 63;
    const int g    = lane >> 4;
    const int l    = lane & 15;
    int pid = blockIdx.x * 16 + wave * 4 + g;   // 0 .. B*HW4-1 (groups never cross b)
    int b  = pid / HW4;
    int hw = pid % HW4;

    const f32x4 refc = *reinterpret_cast<const f32x4*>(
        feat + ((size_t)b * HW4 + hw) * C_ + l * 4);

    f32x4 accv[D_] = {};
    float den[D_]  = {0.f, 0.f, 0.f, 0.f, 0.f};

#pragma unroll
    for (int v = 0; v < V_; v++) {
        const float* fimg = feat + (size_t)(B_ + b * V_ + v) * HW4 * C_;
        const int rbase = ((b * V_ + v) * D_) * HW4 + hw;
#pragma unroll
        for (int d = 0; d < D_; d++) {
            int   rec = sm[rbase + d * HW4];
            f32x4 wv  = sw[rbase + d * HW4];
            int off00 = rec & 0x7FFF;
            int off10 = (rec >> 15) & 0x7FFF;
            const float* p0 = fimg + (size_t)off00 * C_ + l * 4;
            const float* p1 = fimg + (size_t)off10 * C_ + l * 4;
            f32x4 f00 = *reinterpret_cast<const f32x4*>(p0);
            f32x4 f01 = *reinterpret_cast<const f32x4*>(p0 + C_);
            f32x4 f10 = *reinterpret_cast<const f32x4*>(p1);
            f32x4 f11 = *reinterpret_cast<const f32x4*>(p1 + C_);
            accv[d] += f00 * wv[0] + f01 * wv[1] + f10 * wv[2] + f11 * wv[3];
            den[d]  += (float)((rec >> 30) & 1);
        }
    }

#pragma unroll
    for (int d = 0; d < D_; d++) {
        f32x4 pr = refc * accv[d];
        float s = (pr[0] + pr[1]) + (pr[2] + pr[3]);
        s += __shfl_xor(s, 1, 64);
        s += __shfl_xor(s, 2, 64);
        s += __shfl_xor(s, 4, 64);
        s += __shfl_xor(s, 8, 64);
        if (l == 0) {
            out[((size_t)b * D_ + d) * HW4 + hw] =
                (s * (1.0f / (float)C_)) / fmaxf(den[d], 1.0f);
        }
    }
}

extern "C" void kernel_launch(void* const* d_in, const int* in_sizes, int n_in,
                              void* d_out, int out_size, void* d_ws, size_t ws_size,
                              hipStream_t stream) {
    const float* ref_img  = (const float*)d_in[0];
    const float* ngh_img  = (const float*)d_in[1];
    const float* poses    = (const float*)d_in[2];
    const int*   is_valid = (const int*)  d_in[3];
    const float* K        = (const float*)d_in[4];
    const float* dc       = (const float*)d_in[5];
    const float* w1 = (const float*)d_in[6];
    const float* b1 = (const float*)d_in[7];
    const float* w2 = (const float*)d_in[8];
    const float* b2 = (const float*)d_in[9];
    const float* w3 = (const float*)d_in[10];
    const float* b3 = (const float*)d_in[11];
    float* out = (float*)d_out;

    float* ws = (float*)d_ws;
    ushort* f1hi = (ushort*)(ws + OFF_F1HI);
    ushort* f1lo = (ushort*)(ws + OFF_F1LO);
    ushort* f2hi = (ushort*)(ws + OFF_F2HI);
    ushort* f2lo = (ushort*)(ws + OFF_F2LO);
    ushort* inhi = (ushort*)(ws + OFF_INHI);  // aliases f2 region (dead after conv1)
    ushort* inlo = (ushort*)(ws + OFF_INLO);
    float*  f3   = ws + OFF_F3;               // overlaps f1hi (dead after conv2)
    f32x4*  sw   = (f32x4*)(ws + OFF_SAMPW);  // aliases f1lo (dead after conv2)
    int*    sm   = (int*)  (ws + OFF_SAMPM);
    float*  geom = ws + OFF_GEOM;
    ushort* w1p  = (ushort*)(ws + OFF_W1P);
    ushort* w2p  = (ushort*)(ws + OFF_W2P);
    ushort* w3p  = (ushort*)(ws + OFF_W3P);

    geom_kernel<<<1, 64, 0, stream>>>(poses, K, geom);
    packw1_kernel<<<24, 256, 0, stream>>>(w1, w1p);
    packw_kernel<<<(4*9*64*8 + 255)/256, 256, 0, stream>>>(w2, w2p, C1, 9, 18432);
    packw_kernel<<<(4*18*64*8 + 255)/256, 256, 0, stream>>>(w3, w3p, C_, 18, 36864);
    packin_kernel<<<(NIMG*3*PIH*PIW + 255)/256, 256, 0, stream>>>(ref_img, ngh_img, inhi, inlo);

    conv1_mfma<<<dim3(H2*W2/128, NIMG), 256, 0, stream>>>(inhi, inlo, w1p, b1, f1hi, f1lo);
    {
        const int ztot = NIMG*(2*P1W + 2*(P1H-2))*C1 + NIMG*(2*P2W + 2*(P2H-2))*C_;
        zerob_kernel<<<(ztot + 255)/256, 256, 0, stream>>>(f1hi, f1lo, f2hi, f2lo);
    }
    conv2_mfma<<<dim3(H4*W4/128, NIMG), 256, 0, stream>>>(f1hi, f1lo, w2p, b2, f2hi, f2lo);
    // samp writes into the f1lo alias -> must follow conv2 (stream-ordered)
    samp_kernel<<<(B_*V_*D_*HW4 + 255)/256, 256, 0, stream>>>(geom, dc, is_valid, sw, sm);
    conv3_mfma<<<dim3(H4*W4/128, NIMG), 256, 0, stream>>>(f2hi, f2lo, w3p, b3, f3);

    warpcost_kernel<<<(B_*HW4)/16, 256, 0, stream>>>(f3, sw, sm, out);
}